// Round 1
// baseline (3278.417 us; speedup 1.0000x reference)
//
#include <hip/hip_runtime.h>

#define NN 50000
#define NE 800000
#define FIN 80
#define H 128
#define H2 256
#define NG 64
#define NCLS 10
#define BN_EPS 1e-5f

// ---------------------------------------------------------------------------
// Generic tiled fp32 GEMM: C[M,Nn] = act(A[M,K] @ W[K,Nn] + bias (+resid))
// BM=BN=128, BK=16, 256 threads, 8x8 register blocking.
// ---------------------------------------------------------------------------
__global__ __launch_bounds__(256, 4)
void gemm_kernel(const float* __restrict__ A, const float* __restrict__ W,
                 const float* __restrict__ bias, const float* __restrict__ resid,
                 float* __restrict__ C, int M, int K, int Nn, int relu)
{
    __shared__ float aT[16][128];   // A tile, transposed: aT[k][m]
    __shared__ float wsh[16][128];  // W tile: wsh[k][n]

    const int tid = threadIdx.x;
    const int m0 = blockIdx.x * 128;
    const int n0 = blockIdx.y * 128;
    const int mg = tid >> 4;        // 0..15
    const int ng = tid & 15;        // 0..15
    const int rm = mg * 8;
    const int rn = ng * 8;

    float acc[8][8];
#pragma unroll
    for (int i = 0; i < 8; ++i)
#pragma unroll
        for (int j = 0; j < 8; ++j) acc[i][j] = 0.f;

    const int lm = tid & 127;       // A-load: row within tile
    const int kq = (tid >> 7) * 8;  // A-load: k offset (0 or 8)
    const int wk = tid >> 4;        // W-load: k row 0..15
    const int wj = (tid & 15) * 8;  // W-load: col offset

    for (int k0 = 0; k0 < K; k0 += 16) {
        // ---- stage A tile (transposed) ----
        {
            const int gm = m0 + lm;
            if (gm < M) {
                const float4 v0 = *(const float4*)&A[(size_t)gm * K + k0 + kq];
                const float4 v1 = *(const float4*)&A[(size_t)gm * K + k0 + kq + 4];
                aT[kq + 0][lm] = v0.x; aT[kq + 1][lm] = v0.y;
                aT[kq + 2][lm] = v0.z; aT[kq + 3][lm] = v0.w;
                aT[kq + 4][lm] = v1.x; aT[kq + 5][lm] = v1.y;
                aT[kq + 6][lm] = v1.z; aT[kq + 7][lm] = v1.w;
            } else {
#pragma unroll
                for (int i = 0; i < 8; ++i) aT[kq + i][lm] = 0.f;
            }
        }
        // ---- stage W tile ----
        {
            const float4 w0 = *(const float4*)&W[(size_t)(k0 + wk) * Nn + n0 + wj];
            const float4 w1 = *(const float4*)&W[(size_t)(k0 + wk) * Nn + n0 + wj + 4];
            *(float4*)&wsh[wk][wj]     = w0;
            *(float4*)&wsh[wk][wj + 4] = w1;
        }
        __syncthreads();
#pragma unroll
        for (int k = 0; k < 16; ++k) {
            const float4 a0 = *(const float4*)&aT[k][rm];
            const float4 a1 = *(const float4*)&aT[k][rm + 4];
            const float4 b0 = *(const float4*)&wsh[k][rn];
            const float4 b1 = *(const float4*)&wsh[k][rn + 4];
            const float av[8] = {a0.x, a0.y, a0.z, a0.w, a1.x, a1.y, a1.z, a1.w};
            const float bv[8] = {b0.x, b0.y, b0.z, b0.w, b1.x, b1.y, b1.z, b1.w};
#pragma unroll
            for (int i = 0; i < 8; ++i)
#pragma unroll
                for (int j = 0; j < 8; ++j)
                    acc[i][j] = fmaf(av[i], bv[j], acc[i][j]);
        }
        __syncthreads();
    }

    // ---- epilogue ----
    float bv[8];
#pragma unroll
    for (int j = 0; j < 8; ++j) bv[j] = bias[n0 + rn + j];
#pragma unroll
    for (int i = 0; i < 8; ++i) {
        const int gm = m0 + rm + i;
        if (gm >= M) continue;
        float o[8];
#pragma unroll
        for (int j = 0; j < 8; ++j) o[j] = acc[i][j] + bv[j];
        if (resid) {
#pragma unroll
            for (int j = 0; j < 8; ++j) o[j] += resid[(size_t)gm * Nn + n0 + rn + j];
        }
        if (relu) {
#pragma unroll
            for (int j = 0; j < 8; ++j) o[j] = fmaxf(o[j], 0.f);
        }
        *(float4*)&C[(size_t)gm * Nn + n0 + rn]     = make_float4(o[0], o[1], o[2], o[3]);
        *(float4*)&C[(size_t)gm * Nn + n0 + rn + 4] = make_float4(o[4], o[5], o[6], o[7]);
    }
}

// ---------------------------------------------------------------------------
// Edge message + scatter-add:  agg[dst] += relu(h[src] + edge_attr @ We + be)
// 256 threads = 2 edges per iteration (128 channels each).
// ---------------------------------------------------------------------------
__global__ __launch_bounds__(256)
void edge_kernel(const float* __restrict__ h, const int* __restrict__ ei,
                 const float* __restrict__ ea, const float* __restrict__ We,
                 const float* __restrict__ be, float* __restrict__ agg)
{
    __shared__ float sW[16][H];
    __shared__ float sbe[H];
    const int tid = threadIdx.x;
    {
        const int k = tid >> 4;
        const int j = (tid & 15) * 8;
        *(float4*)&sW[k][j]     = *(const float4*)&We[k * H + j];
        *(float4*)&sW[k][j + 4] = *(const float4*)&We[k * H + j + 4];
        if (tid < H) sbe[tid] = be[tid];
    }
    __syncthreads();

    const int c = tid & (H - 1);
    const int half = tid >> 7;
    for (int e = blockIdx.x * 2 + half; e < NE; e += gridDim.x * 2) {
        const int src = ei[e];
        const int dst = ei[NE + e];
        const float4 a0 = *(const float4*)&ea[e * 16];
        const float4 a1 = *(const float4*)&ea[e * 16 + 4];
        const float4 a2 = *(const float4*)&ea[e * 16 + 8];
        const float4 a3 = *(const float4*)&ea[e * 16 + 12];
        float acc = sbe[c];
        acc = fmaf(a0.x, sW[0][c], acc);
        acc = fmaf(a0.y, sW[1][c], acc);
        acc = fmaf(a0.z, sW[2][c], acc);
        acc = fmaf(a0.w, sW[3][c], acc);
        acc = fmaf(a1.x, sW[4][c], acc);
        acc = fmaf(a1.y, sW[5][c], acc);
        acc = fmaf(a1.z, sW[6][c], acc);
        acc = fmaf(a1.w, sW[7][c], acc);
        acc = fmaf(a2.x, sW[8][c], acc);
        acc = fmaf(a2.y, sW[9][c], acc);
        acc = fmaf(a2.z, sW[10][c], acc);
        acc = fmaf(a2.w, sW[11][c], acc);
        acc = fmaf(a3.x, sW[12][c], acc);
        acc = fmaf(a3.y, sW[13][c], acc);
        acc = fmaf(a3.z, sW[14][c], acc);
        acc = fmaf(a3.w, sW[15][c], acc);
        const float msg = fmaxf(h[src * H + c] + acc, 0.f);
        atomicAdd(&agg[dst * H + c], msg);
    }
}

// ---------------------------------------------------------------------------
// Small elementwise / reduction kernels
// ---------------------------------------------------------------------------
__global__ void concat_kernel(const float* __restrict__ x, const float* __restrict__ pe,
                              float* __restrict__ xin)
{
    const int i = blockIdx.x * 256 + threadIdx.x;   // grid sized exactly NN*FIN/256
    const int row = i / FIN;
    const int c = i - row * FIN;
    xin[i] = (c < 64) ? x[row * 64 + c] : pe[row * 16 + (c - 64)];
}

__global__ void zprep_kernel(const float* __restrict__ h, float* __restrict__ zin,
                             const float* __restrict__ eps, int l)
{
    const int i = blockIdx.x * 256 + threadIdx.x;   // grid exactly NN*H/256
    const float e1 = 1.0f + eps[l];
    zin[i] = fmaf(e1, h[i], zin[i]);   // zin aliases agg: z = (1+eps)*h + agg
}

__global__ void post_gin_kernel(const float* __restrict__ t, const float* __restrict__ h,
                                const float* __restrict__ ab, float* __restrict__ zin)
{
    const int i = blockIdx.x * 256 + threadIdx.x;
    const int c = i & (H - 1);
    zin[i] = fmaxf(fmaf(t[i], ab[c], ab[H + c]), 0.f) + h[i];
}

__global__ void bn_apply_kernel(const float* __restrict__ u, const float* __restrict__ ab,
                                float* __restrict__ h)
{
    const int i = blockIdx.x * 256 + threadIdx.x;
    const int c = i & (H - 1);
    h[i] = fmaf(u[i], ab[c], ab[H + c]);
}

__global__ void bn_stats_kernel(const float* __restrict__ X, float* __restrict__ stats, int n)
{
    __shared__ float ssum[256];
    __shared__ float ssq[256];
    const int tid = threadIdx.x;
    const int c = tid & (H - 1);
    const int sub = tid >> 7;
    const int r0 = blockIdx.x * 512;
    const int rend = min(r0 + 512, n);
    float s = 0.f, q = 0.f;
    for (int r = r0 + sub; r < rend; r += 2) {
        const float v = X[(size_t)r * H + c];
        s += v;
        q = fmaf(v, v, q);
    }
    ssum[tid] = s;
    ssq[tid] = q;
    __syncthreads();
    if (sub == 0) {
        s = ssum[c] + ssum[c + 128];
        q = ssq[c] + ssq[c + 128];
        atomicAdd(&stats[c], s);
        atomicAdd(&stats[H + c], q);
    }
}

__global__ void bn_finalize_kernel(const float* __restrict__ stats, const float* __restrict__ g,
                                   const float* __restrict__ b, float* __restrict__ ab,
                                   float inv_n)
{
    const int c = threadIdx.x;  // 128 threads
    const float mean = stats[c] * inv_n;
    const float var = stats[H + c] * inv_n - mean * mean;
    const float a = g[c] * rsqrtf(var + BN_EPS);
    ab[c] = a;
    ab[H + c] = fmaf(-mean, a, b[c]);
}

// batch is sorted -> run-length accumulate, flush one atomic per run
__global__ void pool_kernel(const float* __restrict__ h, const int* __restrict__ batch,
                            float* __restrict__ pool, float* __restrict__ cnt, int n)
{
    const int c = threadIdx.x & (H - 1);
    const int half = threadIdx.x >> 7;
    const int r0 = blockIdx.x * 256 + half * 128;
    if (r0 >= n) return;
    const int rend = min(r0 + 128, n);
    int gprev = batch[r0];
    float acc = 0.f;
    int run = 0;
    for (int r = r0; r < rend; ++r) {
        const int g = batch[r];
        if (g != gprev) {
            atomicAdd(&pool[gprev * H + c], acc);
            if (c == 0) atomicAdd(&cnt[gprev], (float)run);
            acc = 0.f; run = 0; gprev = g;
        }
        acc += h[(size_t)r * H + c];
        run++;
    }
    atomicAdd(&pool[gprev * H + c], acc);
    if (c == 0) atomicAdd(&cnt[gprev], (float)run);
}

__global__ void readout_kernel(const float* __restrict__ pool, const float* __restrict__ cnt,
                               const float* __restrict__ Wr1, const float* __restrict__ br1,
                               const float* __restrict__ Wr2, const float* __restrict__ br2,
                               float* __restrict__ out)
{
    __shared__ float hg[H];
    __shared__ float r1[H];
    const int g = blockIdx.x;
    const int j = threadIdx.x;  // 128 threads
    hg[j] = pool[g * H + j] / fmaxf(cnt[g], 1.0f);
    __syncthreads();
    float acc = br1[j];
    for (int k = 0; k < H; ++k) acc = fmaf(hg[k], Wr1[k * H + j], acc);
    r1[j] = fmaxf(acc, 0.f);
    __syncthreads();
    if (j < NCLS) {
        float o = br2[j];
        for (int k = 0; k < H; ++k) o = fmaf(r1[k], Wr2[k * NCLS + j], o);
        out[g * NCLS + j] = o;
    }
}

// ---------------------------------------------------------------------------
extern "C" void kernel_launch(void* const* d_in, const int* in_sizes, int n_in,
                              void* d_out, int out_size, void* d_ws, size_t ws_size,
                              hipStream_t stream)
{
    const float* x       = (const float*)d_in[0];
    const float* pe      = (const float*)d_in[1];
    const int*   ei      = (const int*)d_in[2];
    const float* ea      = (const float*)d_in[3];
    const int*   batch   = (const int*)d_in[4];
    const float* W_in    = (const float*)d_in[5];
    const float* b_in    = (const float*)d_in[6];
    const float* We_edge = (const float*)d_in[7];
    const float* be_edge = (const float*)d_in[8];
    const float* eps     = (const float*)d_in[9];
    const float* W1g     = (const float*)d_in[10];
    const float* b1g     = (const float*)d_in[11];
    const float* W2g     = (const float*)d_in[12];
    const float* b2g     = (const float*)d_in[13];
    const float* bn1g    = (const float*)d_in[14];
    const float* bn1b    = (const float*)d_in[15];
    const float* W1f     = (const float*)d_in[16];
    const float* b1f     = (const float*)d_in[17];
    const float* W2f     = (const float*)d_in[18];
    const float* b2f     = (const float*)d_in[19];
    const float* bn2g    = (const float*)d_in[20];
    const float* bn2b    = (const float*)d_in[21];
    const float* Wr1     = (const float*)d_in[22];
    const float* br1     = (const float*)d_in[23];
    const float* Wr2     = (const float*)d_in[24];
    const float* br2     = (const float*)d_in[25];
    float* out = (float*)d_out;

    const size_t NH = (size_t)NN * H;
    float* hbuf  = (float*)d_ws;          // [NN,H]
    float* aggb  = hbuf + NH;             // [NN,H]   agg, then reused as z ("zin")
    float* tbuf  = aggb + NH;             // [NN,H]   GIN-MLP out t, then FFN out u
    float* z1    = tbuf + NH;             // [NN,H2]  MLP hidden; also xin at start
    float* stats = z1 + (size_t)NN * H2;  // [4*H]  sum1,sq1,sum2,sq2
    float* bnp   = stats + 4 * H;         // [4*H]  a1,s1,a2,s2
    float* pool  = bnp + 4 * H;           // [NG,H]
    float* cnt   = pool + NG * H;         // [NG]

    const dim3 blk(256);
    const dim3 gemm_g1((NN + 127) / 128, 1);
    const dim3 gemm_g2((NN + 127) / 128, 2);
    const int ew_grid = (int)(NH / 256);        // 25000, exact
    const float inv_n = 1.0f / (float)NN;

    // ---- input projection: h = relu([x||pe] @ W_in + b_in) ----
    concat_kernel<<<(NN * FIN) / 256, blk, 0, stream>>>(x, pe, z1);
    gemm_kernel<<<gemm_g1, blk, 0, stream>>>(z1, W_in, b_in, nullptr, hbuf, NN, FIN, H, 1);

    for (int l = 0; l < 4; ++l) {
        hipMemsetAsync(aggb, 0, NH * sizeof(float), stream);
        hipMemsetAsync(stats, 0, 4 * H * sizeof(float), stream);

        edge_kernel<<<4096, blk, 0, stream>>>(hbuf, ei, ea, We_edge + (size_t)l * 16 * H,
                                              be_edge + (size_t)l * H, aggb);
        zprep_kernel<<<ew_grid, blk, 0, stream>>>(hbuf, aggb, eps, l);

        // GIN MLP: t = relu(z @ W1g + b1g) @ W2g + b2g
        gemm_kernel<<<gemm_g2, blk, 0, stream>>>(aggb, W1g + (size_t)l * H * H2,
                                                 b1g + (size_t)l * H2, nullptr, z1, NN, H, H2, 1);
        gemm_kernel<<<gemm_g1, blk, 0, stream>>>(z1, W2g + (size_t)l * H2 * H,
                                                 b2g + (size_t)l * H, nullptr, tbuf, NN, H2, H, 0);
        bn_stats_kernel<<<(NN + 511) / 512, blk, 0, stream>>>(tbuf, stats, NN);
        bn_finalize_kernel<<<1, H, 0, stream>>>(stats, bn1g + (size_t)l * H,
                                                bn1b + (size_t)l * H, bnp, inv_n);
        // z = relu(bn1(t)) + h   -> into aggb ("zin")
        post_gin_kernel<<<ew_grid, blk, 0, stream>>>(tbuf, hbuf, bnp, aggb);

        // FFN: u = relu(z @ W1f + b1f) @ W2f + b2f + z
        gemm_kernel<<<gemm_g2, blk, 0, stream>>>(aggb, W1f + (size_t)l * H * H2,
                                                 b1f + (size_t)l * H2, nullptr, z1, NN, H, H2, 1);
        gemm_kernel<<<gemm_g1, blk, 0, stream>>>(z1, W2f + (size_t)l * H2 * H,
                                                 b2f + (size_t)l * H, aggb, tbuf, NN, H2, H, 0);
        bn_stats_kernel<<<(NN + 511) / 512, blk, 0, stream>>>(tbuf, stats + 2 * H, NN);
        bn_finalize_kernel<<<1, H, 0, stream>>>(stats + 2 * H, bn2g + (size_t)l * H,
                                                bn2b + (size_t)l * H, bnp + 2 * H, inv_n);
        // h = bn2(u)
        bn_apply_kernel<<<ew_grid, blk, 0, stream>>>(tbuf, bnp + 2 * H, hbuf);
    }

    // ---- global mean pool + readout ----
    hipMemsetAsync(pool, 0, (NG * H + NG) * sizeof(float), stream);
    pool_kernel<<<(NN + 255) / 256, blk, 0, stream>>>(hbuf, batch, pool, cnt, NN);
    readout_kernel<<<NG, H, 0, stream>>>(pool, cnt, Wr1, br1, Wr2, br2, out);
}

// Round 2
// 2094.715 us; speedup vs baseline: 1.5651x; 1.5651x over previous
//
#include <hip/hip_runtime.h>

#define NN 50000
#define NE 800000
#define FIN 80
#define H 128
#define H2 256
#define NG 64
#define NCLS 10
#define BN_EPS 1e-5f

// ---------------------------------------------------------------------------
// Generic tiled fp32 GEMM: C[M,Nn] = act(A[M,K] @ W[K,Nn] + bias (+resid))
// BM=BN=128, BK=16, 256 threads, 8x8 register blocking.
// Optional fused BN-stats: atomic per-column sum / sumsq into stats[0..Nn),
// stats[Nn..2Nn). Only used when grid.y==1 (Nn==128).
// ---------------------------------------------------------------------------
__global__ __launch_bounds__(256, 4)
void gemm_kernel(const float* __restrict__ A, const float* __restrict__ W,
                 const float* __restrict__ bias, const float* __restrict__ resid,
                 float* __restrict__ C, int M, int K, int Nn, int relu,
                 float* __restrict__ stats)
{
    __shared__ float aT[16][128];   // A tile, transposed: aT[k][m]
    __shared__ float wsh[16][128];  // W tile: wsh[k][n]

    const int tid = threadIdx.x;
    const int m0 = blockIdx.x * 128;
    const int n0 = blockIdx.y * 128;
    const int mg = tid >> 4;        // 0..15
    const int ng = tid & 15;        // 0..15
    const int rm = mg * 8;
    const int rn = ng * 8;

    float acc[8][8];
#pragma unroll
    for (int i = 0; i < 8; ++i)
#pragma unroll
        for (int j = 0; j < 8; ++j) acc[i][j] = 0.f;

    const int lm = tid & 127;       // A-load: row within tile
    const int kq = (tid >> 7) * 8;  // A-load: k offset (0 or 8)
    const int wk = tid >> 4;        // W-load: k row 0..15
    const int wj = (tid & 15) * 8;  // W-load: col offset

    for (int k0 = 0; k0 < K; k0 += 16) {
        {
            const int gm = m0 + lm;
            if (gm < M) {
                const float4 v0 = *(const float4*)&A[(size_t)gm * K + k0 + kq];
                const float4 v1 = *(const float4*)&A[(size_t)gm * K + k0 + kq + 4];
                aT[kq + 0][lm] = v0.x; aT[kq + 1][lm] = v0.y;
                aT[kq + 2][lm] = v0.z; aT[kq + 3][lm] = v0.w;
                aT[kq + 4][lm] = v1.x; aT[kq + 5][lm] = v1.y;
                aT[kq + 6][lm] = v1.z; aT[kq + 7][lm] = v1.w;
            } else {
#pragma unroll
                for (int i = 0; i < 8; ++i) aT[kq + i][lm] = 0.f;
            }
        }
        {
            const float4 w0 = *(const float4*)&W[(size_t)(k0 + wk) * Nn + n0 + wj];
            const float4 w1 = *(const float4*)&W[(size_t)(k0 + wk) * Nn + n0 + wj + 4];
            *(float4*)&wsh[wk][wj]     = w0;
            *(float4*)&wsh[wk][wj + 4] = w1;
        }
        __syncthreads();
#pragma unroll
        for (int k = 0; k < 16; ++k) {
            const float4 a0 = *(const float4*)&aT[k][rm];
            const float4 a1 = *(const float4*)&aT[k][rm + 4];
            const float4 b0 = *(const float4*)&wsh[k][rn];
            const float4 b1 = *(const float4*)&wsh[k][rn + 4];
            const float av[8] = {a0.x, a0.y, a0.z, a0.w, a1.x, a1.y, a1.z, a1.w};
            const float bv[8] = {b0.x, b0.y, b0.z, b0.w, b1.x, b1.y, b1.z, b1.w};
#pragma unroll
            for (int i = 0; i < 8; ++i)
#pragma unroll
                for (int j = 0; j < 8; ++j)
                    acc[i][j] = fmaf(av[i], bv[j], acc[i][j]);
        }
        __syncthreads();
    }

    // ---- epilogue ----
    float bv[8];
#pragma unroll
    for (int j = 0; j < 8; ++j) bv[j] = bias[n0 + rn + j];
    float s[8], q[8];
#pragma unroll
    for (int j = 0; j < 8; ++j) { s[j] = 0.f; q[j] = 0.f; }
#pragma unroll
    for (int i = 0; i < 8; ++i) {
        const int gm = m0 + rm + i;
        if (gm >= M) continue;
        float o[8];
#pragma unroll
        for (int j = 0; j < 8; ++j) o[j] = acc[i][j] + bv[j];
        if (resid) {
#pragma unroll
            for (int j = 0; j < 8; ++j) o[j] += resid[(size_t)gm * Nn + n0 + rn + j];
        }
        if (relu) {
#pragma unroll
            for (int j = 0; j < 8; ++j) o[j] = fmaxf(o[j], 0.f);
        }
        if (stats) {
#pragma unroll
            for (int j = 0; j < 8; ++j) { s[j] += o[j]; q[j] = fmaf(o[j], o[j], q[j]); }
        }
        *(float4*)&C[(size_t)gm * Nn + n0 + rn]     = make_float4(o[0], o[1], o[2], o[3]);
        *(float4*)&C[(size_t)gm * Nn + n0 + rn + 4] = make_float4(o[4], o[5], o[6], o[7]);
    }

    if (stats) {
        __syncthreads();
#pragma unroll
        for (int j = 0; j < 8; ++j) aT[mg][rn + j] = s[j];
        __syncthreads();
        if (tid < 128) {
            float v = 0.f;
#pragma unroll
            for (int r = 0; r < 16; ++r) v += aT[r][tid];
            atomicAdd(&stats[n0 + tid], v);
        }
        __syncthreads();
#pragma unroll
        for (int j = 0; j < 8; ++j) aT[mg][rn + j] = q[j];
        __syncthreads();
        if (tid < 128) {
            float v = 0.f;
#pragma unroll
            for (int r = 0; r < 16; ++r) v += aT[r][tid];
            atomicAdd(&stats[Nn + n0 + tid], v);
        }
    }
}

// ---------------------------------------------------------------------------
// CSR build: histogram by dst, scan, scatter (also permutes edge_attr into
// dst-sorted order so the per-layer aggregation streams it coalesced).
// ---------------------------------------------------------------------------
__global__ void hist_kernel(const int* __restrict__ ei, int* __restrict__ deg)
{
    const int e = blockIdx.x * 256 + threadIdx.x;
    if (e < NE) atomicAdd(&deg[ei[NE + e]], 1);
}

__global__ __launch_bounds__(1024)
void scan_kernel(const int* __restrict__ deg, int* __restrict__ rowptr,
                 int* __restrict__ cursor)
{
    __shared__ int part[1024];
    const int tid = threadIdx.x;
    const int c0 = tid * 49;
    const int c1 = min(c0 + 49, NN);
    int sum = 0;
    for (int i = c0; i < c1; ++i) sum += deg[i];
    part[tid] = sum;
    __syncthreads();
    for (int off = 1; off < 1024; off <<= 1) {
        const int v = (tid >= off) ? part[tid - off] : 0;
        __syncthreads();
        part[tid] += v;
        __syncthreads();
    }
    int base = (tid == 0) ? 0 : part[tid - 1];
    for (int i = c0; i < c1; ++i) {
        rowptr[i] = base;
        cursor[i] = base;
        base += deg[i];
    }
    if (tid == 1023) rowptr[NN] = part[1023];
}

__global__ void scatter_kernel(const int* __restrict__ ei, const float* __restrict__ ea,
                               int* __restrict__ cursor, int* __restrict__ src_s,
                               float* __restrict__ ea_s)
{
    const int e = blockIdx.x * 256 + threadIdx.x;
    if (e >= NE) return;
    const int d = ei[NE + e];
    const int pos = atomicAdd(&cursor[d], 1);
    src_s[pos] = ei[e];
    const float4* sp = (const float4*)&ea[(size_t)e * 16];
    float4* dp = (float4*)&ea_s[(size_t)pos * 16];
    dp[0] = sp[0]; dp[1] = sp[1]; dp[2] = sp[2]; dp[3] = sp[3];
}

// ---------------------------------------------------------------------------
// Per-layer aggregation (CSR gather, no atomics). One wave per node; lane
// owns channels 2*lane, 2*lane+1. Edge-lin weights in registers; ea values
// broadcast via shuffles. Fuses zprep: z = (1+eps)*h + sum relu(h[src]+elin).
// ---------------------------------------------------------------------------
__global__ __launch_bounds__(256)
void agg_kernel(const float* __restrict__ h, const int* __restrict__ rowptr,
                const int* __restrict__ src_s, const float* __restrict__ ea_s,
                const float* __restrict__ We, const float* __restrict__ be,
                const float* __restrict__ eps, int l, float* __restrict__ z)
{
    const int lane = threadIdx.x & 63;
    const int w = threadIdx.x >> 6;
    const int n = blockIdx.x * 4 + w;
    if (n >= NN) return;

    float w0[16], w1[16];
#pragma unroll
    for (int k = 0; k < 16; ++k) {
        const float2 wv = *(const float2*)&We[k * H + 2 * lane];
        w0[k] = wv.x; w1[k] = wv.y;
    }
    const float2 bev = *(const float2*)&be[2 * lane];

    int beg = rowptr[n];
    int end = rowptr[n + 1];
    beg = __builtin_amdgcn_readfirstlane(beg);
    end = __builtin_amdgcn_readfirstlane(end);

    const float e1 = 1.0f + eps[l];
    const float2 hv0 = *(const float2*)&h[(size_t)n * H + 2 * lane];
    float acc0 = e1 * hv0.x;
    float acc1 = e1 * hv0.y;

    for (int i0 = beg; i0 < end; i0 += 4) {
        const int idx = min(i0 * 16 + lane, NE * 16 - 1);
        const float xv = ea_s[idx];
        const int jn = min(4, end - i0);
        for (int j = 0; j < jn; ++j) {
            int src = src_s[i0 + j];
            src = __builtin_amdgcn_readfirstlane(src);
            const float2 hv = *(const float2*)&h[(size_t)src * H + 2 * lane];
            float s0 = bev.x, s1 = bev.y;
#pragma unroll
            for (int k = 0; k < 16; ++k) {
                const float a = __shfl(xv, j * 16 + k, 64);
                s0 = fmaf(a, w0[k], s0);
                s1 = fmaf(a, w1[k], s1);
            }
            acc0 += fmaxf(hv.x + s0, 0.f);
            acc1 += fmaxf(hv.y + s1, 0.f);
        }
    }
    *(float2*)&z[(size_t)n * H + 2 * lane] = make_float2(acc0, acc1);
}

// ---------------------------------------------------------------------------
// Small elementwise / BN kernels
// ---------------------------------------------------------------------------
__global__ void concat_kernel(const float* __restrict__ x, const float* __restrict__ pe,
                              float* __restrict__ xin)
{
    const int i = blockIdx.x * 256 + threadIdx.x;   // grid sized exactly NN*FIN/256
    const int row = i / FIN;
    const int c = i - row * FIN;
    xin[i] = (c < 64) ? x[row * 64 + c] : pe[row * 16 + (c - 64)];
}

__global__ void post_gin_kernel(const float* __restrict__ t, const float* __restrict__ h,
                                const float* __restrict__ ab, float* __restrict__ zin)
{
    const int i = blockIdx.x * 256 + threadIdx.x;
    const int c = i & (H - 1);
    zin[i] = fmaxf(fmaf(t[i], ab[c], ab[H + c]), 0.f) + h[i];
}

__global__ void bn_apply_kernel(const float* __restrict__ u, const float* __restrict__ ab,
                                float* __restrict__ h)
{
    const int i = blockIdx.x * 256 + threadIdx.x;
    const int c = i & (H - 1);
    h[i] = fmaf(u[i], ab[c], ab[H + c]);
}

__global__ void bn_finalize_kernel(const float* __restrict__ stats, const float* __restrict__ g,
                                   const float* __restrict__ b, float* __restrict__ ab,
                                   float inv_n)
{
    const int c = threadIdx.x;  // 128 threads
    const float mean = stats[c] * inv_n;
    const float var = stats[H + c] * inv_n - mean * mean;
    const float a = g[c] * rsqrtf(var + BN_EPS);
    ab[c] = a;
    ab[H + c] = fmaf(-mean, a, b[c]);
}

// batch is sorted -> run-length accumulate, flush one atomic per run
__global__ void pool_kernel(const float* __restrict__ h, const int* __restrict__ batch,
                            float* __restrict__ pool, float* __restrict__ cnt, int n)
{
    const int c = threadIdx.x & (H - 1);
    const int half = threadIdx.x >> 7;
    const int r0 = blockIdx.x * 256 + half * 128;
    if (r0 >= n) return;
    const int rend = min(r0 + 128, n);
    int gprev = batch[r0];
    float acc = 0.f;
    int run = 0;
    for (int r = r0; r < rend; ++r) {
        const int g = batch[r];
        if (g != gprev) {
            atomicAdd(&pool[gprev * H + c], acc);
            if (c == 0) atomicAdd(&cnt[gprev], (float)run);
            acc = 0.f; run = 0; gprev = g;
        }
        acc += h[(size_t)r * H + c];
        run++;
    }
    atomicAdd(&pool[gprev * H + c], acc);
    if (c == 0) atomicAdd(&cnt[gprev], (float)run);
}

__global__ void readout_kernel(const float* __restrict__ pool, const float* __restrict__ cnt,
                               const float* __restrict__ Wr1, const float* __restrict__ br1,
                               const float* __restrict__ Wr2, const float* __restrict__ br2,
                               float* __restrict__ out)
{
    __shared__ float hg[H];
    __shared__ float r1[H];
    const int g = blockIdx.x;
    const int j = threadIdx.x;  // 128 threads
    hg[j] = pool[g * H + j] / fmaxf(cnt[g], 1.0f);
    __syncthreads();
    float acc = br1[j];
    for (int k = 0; k < H; ++k) acc = fmaf(hg[k], Wr1[k * H + j], acc);
    r1[j] = fmaxf(acc, 0.f);
    __syncthreads();
    if (j < NCLS) {
        float o = br2[j];
        for (int k = 0; k < H; ++k) o = fmaf(r1[k], Wr2[k * NCLS + j], o);
        out[g * NCLS + j] = o;
    }
}

// ---------------------------------------------------------------------------
extern "C" void kernel_launch(void* const* d_in, const int* in_sizes, int n_in,
                              void* d_out, int out_size, void* d_ws, size_t ws_size,
                              hipStream_t stream)
{
    const float* x       = (const float*)d_in[0];
    const float* pe      = (const float*)d_in[1];
    const int*   ei      = (const int*)d_in[2];
    const float* ea      = (const float*)d_in[3];
    const int*   batch   = (const int*)d_in[4];
    const float* W_in    = (const float*)d_in[5];
    const float* b_in    = (const float*)d_in[6];
    const float* We_edge = (const float*)d_in[7];
    const float* be_edge = (const float*)d_in[8];
    const float* eps     = (const float*)d_in[9];
    const float* W1g     = (const float*)d_in[10];
    const float* b1g     = (const float*)d_in[11];
    const float* W2g     = (const float*)d_in[12];
    const float* b2g     = (const float*)d_in[13];
    const float* bn1g    = (const float*)d_in[14];
    const float* bn1b    = (const float*)d_in[15];
    const float* W1f     = (const float*)d_in[16];
    const float* b1f     = (const float*)d_in[17];
    const float* W2f     = (const float*)d_in[18];
    const float* b2f     = (const float*)d_in[19];
    const float* bn2g    = (const float*)d_in[20];
    const float* bn2b    = (const float*)d_in[21];
    const float* Wr1     = (const float*)d_in[22];
    const float* br1     = (const float*)d_in[23];
    const float* Wr2     = (const float*)d_in[24];
    const float* br2     = (const float*)d_in[25];
    float* out = (float*)d_out;

    const size_t NH = (size_t)NN * H;
    float* hbuf  = (float*)d_ws;          // [NN,H]
    float* zbuf  = hbuf + NH;             // [NN,H]   z (agg output, GIN input)
    float* tbuf  = zbuf + NH;             // [NN,H]   GIN-MLP out t / FFN out u
    float* z1    = tbuf + NH;             // [NN,H2]  MLP hidden; also xin at start
    float* stats = z1 + (size_t)NN * H2;  // [4*H]  sum1,sq1,sum2,sq2
    float* bnp   = stats + 4 * H;         // [4*H]  a1,s1,a2,s2
    float* pool  = bnp + 4 * H;           // [NG,H]
    float* cnt   = pool + NG * H;         // [NG]
    int*   rowptr = (int*)(cnt + NG);     // [NN+1]
    int*   cursor = rowptr + NN + 1;      // [NN]
    int*   deg    = cursor + NN;          // [NN]
    int*   src_s  = deg + NN;             // [NE]
    float* ea_s   = (float*)(src_s + NE); // [NE,16]

    const dim3 blk(256);
    const dim3 gemm_g1((NN + 127) / 128, 1);
    const dim3 gemm_g2((NN + 127) / 128, 2);
    const int ew_grid = (int)(NH / 256);        // 25000, exact
    const float inv_n = 1.0f / (float)NN;

    // ---- CSR build (once per launch) ----
    hipMemsetAsync(deg, 0, NN * sizeof(int), stream);
    hist_kernel<<<(NE + 255) / 256, blk, 0, stream>>>(ei, deg);
    scan_kernel<<<1, 1024, 0, stream>>>(deg, rowptr, cursor);
    scatter_kernel<<<(NE + 255) / 256, blk, 0, stream>>>(ei, ea, cursor, src_s, ea_s);

    // ---- input projection: h = relu([x||pe] @ W_in + b_in) ----
    concat_kernel<<<(NN * FIN) / 256, blk, 0, stream>>>(x, pe, z1);
    gemm_kernel<<<gemm_g1, blk, 0, stream>>>(z1, W_in, b_in, nullptr, hbuf, NN, FIN, H, 1, nullptr);

    for (int l = 0; l < 4; ++l) {
        hipMemsetAsync(stats, 0, 4 * H * sizeof(float), stream);

        // z = (1+eps)*h + sum_{edges to n} relu(h[src] + ea@We + be)
        agg_kernel<<<(NN + 3) / 4, blk, 0, stream>>>(hbuf, rowptr, src_s, ea_s,
                                                     We_edge + (size_t)l * 16 * H,
                                                     be_edge + (size_t)l * H, eps, l, zbuf);

        // GIN MLP: t = relu(z @ W1g + b1g) @ W2g + b2g   (+fused bn1 stats)
        gemm_kernel<<<gemm_g2, blk, 0, stream>>>(zbuf, W1g + (size_t)l * H * H2,
                                                 b1g + (size_t)l * H2, nullptr, z1, NN, H, H2, 1, nullptr);
        gemm_kernel<<<gemm_g1, blk, 0, stream>>>(z1, W2g + (size_t)l * H2 * H,
                                                 b2g + (size_t)l * H, nullptr, tbuf, NN, H2, H, 0, stats);
        bn_finalize_kernel<<<1, H, 0, stream>>>(stats, bn1g + (size_t)l * H,
                                                bn1b + (size_t)l * H, bnp, inv_n);
        // z = relu(bn1(t)) + h   -> into zbuf
        post_gin_kernel<<<ew_grid, blk, 0, stream>>>(tbuf, hbuf, bnp, zbuf);

        // FFN: u = relu(z @ W1f + b1f) @ W2f + b2f + z   (+fused bn2 stats)
        gemm_kernel<<<gemm_g2, blk, 0, stream>>>(zbuf, W1f + (size_t)l * H * H2,
                                                 b1f + (size_t)l * H2, nullptr, z1, NN, H, H2, 1, nullptr);
        gemm_kernel<<<gemm_g1, blk, 0, stream>>>(z1, W2f + (size_t)l * H2 * H,
                                                 b2f + (size_t)l * H, zbuf, tbuf, NN, H2, H, 0, stats + 2 * H);
        bn_finalize_kernel<<<1, H, 0, stream>>>(stats + 2 * H, bn2g + (size_t)l * H,
                                                bn2b + (size_t)l * H, bnp + 2 * H, inv_n);
        // h = bn2(u)
        bn_apply_kernel<<<ew_grid, blk, 0, stream>>>(tbuf, bnp + 2 * H, hbuf);
    }

    // ---- global mean pool + readout ----
    hipMemsetAsync(pool, 0, (NG * H + NG) * sizeof(float), stream);
    pool_kernel<<<(NN + 255) / 256, blk, 0, stream>>>(hbuf, batch, pool, cnt, NN);
    readout_kernel<<<NG, H, 0, stream>>>(pool, cnt, Wr1, br1, Wr2, br2, out);
}

// Round 3
// 1650.777 us; speedup vs baseline: 1.9860x; 1.2689x over previous
//
#include <hip/hip_runtime.h>
#include <hip/hip_bf16.h>

#define NN 50000
#define NE 800000
#define FIN 80
#define H 128
#define H2 256
#define NG 64
#define NCLS 10
#define BN_EPS 1e-5f

typedef __attribute__((ext_vector_type(8))) short bf16x8;
typedef __attribute__((ext_vector_type(8))) unsigned short us8;
typedef __attribute__((ext_vector_type(4))) float f32x4;

__device__ __forceinline__ unsigned short f2b(float f) {
    __hip_bfloat16 h = __float2bfloat16(f);   // RNE
    return *(unsigned short*)&h;
}
__device__ __forceinline__ float b2f(unsigned short u) {
    unsigned v = (unsigned)u << 16;
    return __uint_as_float(v);
}

// ---------------------------------------------------------------------------
// Weight prep: W[L][K][Nn] fp32 -> per-layer {hi,lo} bf16 planes, k-blocked:
// dst[l][ ((p*KB + kb)*Nn + n)*32 + kk ]  (KB = K/32, kb = k/32, kk = k%32)
// ---------------------------------------------------------------------------
__global__ void wprep_kernel(const float* __restrict__ W, unsigned short* __restrict__ Wt,
                             int K, int Nn)
{
    const int idx = blockIdx.x * 256 + threadIdx.x;   // grid = 4*K*Nn/256 exactly
    const int per = K * Nn;
    const int l = idx / per;
    const int r = idx - l * per;
    const int k = r / Nn;
    const int n = r - k * Nn;
    const float wv = W[idx];
    const unsigned short hi = f2b(wv);
    const unsigned short lo = f2b(wv - b2f(hi));
    const int KB = K >> 5;
    const int kb = k >> 5, kk = k & 31;
    unsigned short* base = Wt + (size_t)l * 2 * per;
    base[((size_t)(0 * KB + kb) * Nn + n) * 32 + kk] = hi;
    base[((size_t)(1 * KB + kb) * Nn + n) * 32 + kk] = lo;
}

// ---------------------------------------------------------------------------
// MFMA GEMM: C[M,Nn] = act(A[M,K] @ (Whi+Wlo) + bias (+resid))
// BM=128, BN=128 (grid.y tiles Nn), BK=32, 256 thr = 4 waves, 16x16x32 bf16.
// ABF: A is bf16 [M,K]; else fp32 (converted in staging).
// CBF: C stored bf16; else fp32.
// stats != null (requires Nn==128, grid.y==1): fused per-column sum/sumsq.
// ---------------------------------------------------------------------------
template<bool ABF, bool CBF>
__global__ __launch_bounds__(256, 2)
void mgemm(const void* __restrict__ Ap, const unsigned short* __restrict__ Wt,
           const float* __restrict__ bias, const float* __restrict__ resid,
           void* __restrict__ Cp, int M, int K, int Nn, int relu,
           float* __restrict__ stats)
{
    __shared__ unsigned short sA[128][32];      // A[m][k]   8 KB
    __shared__ unsigned short sB[2][128][32];   // Bt[p][n][k] 16 KB

    const int tid = threadIdx.x;
    const int m0 = blockIdx.x * 128;
    const int n0 = blockIdx.y * 128;
    const int lane = tid & 63;
    const int w = tid >> 6;
    const int KB = K >> 5;

    f32x4 acc[2][8];
#pragma unroll
    for (int r = 0; r < 2; ++r)
#pragma unroll
        for (int c = 0; c < 8; ++c) acc[r][c] = (f32x4)(0.f);

    const int arow = tid >> 1;
    const int akh = (tid & 1) * 16;
    const int gm = m0 + arow;
    const int fr = lane & 15;        // fragment row/col within 16
    const int fq = (lane >> 4) * 8;  // fragment k offset

    for (int kb = 0; kb < KB; ++kb) {
        const int k0 = kb * 32;
        __syncthreads();
        // ---- stage A ----
        if (ABF) {
            if (gm < M) {
                const unsigned short* Ab = (const unsigned short*)Ap + (size_t)gm * K + k0 + akh;
                *(float4*)&sA[arow][akh]     = *(const float4*)Ab;
                *(float4*)&sA[arow][akh + 8] = *(const float4*)(Ab + 8);
            } else {
                *(float4*)&sA[arow][akh]     = make_float4(0.f, 0.f, 0.f, 0.f);
                *(float4*)&sA[arow][akh + 8] = make_float4(0.f, 0.f, 0.f, 0.f);
            }
        } else {
            if (gm < M) {
                const float* Af = (const float*)Ap + (size_t)gm * K + k0 + akh;
                const float4 v0 = *(const float4*)(Af);
                const float4 v1 = *(const float4*)(Af + 4);
                const float4 v2 = *(const float4*)(Af + 8);
                const float4 v3 = *(const float4*)(Af + 12);
                const float vals[16] = {v0.x, v0.y, v0.z, v0.w, v1.x, v1.y, v1.z, v1.w,
                                        v2.x, v2.y, v2.z, v2.w, v3.x, v3.y, v3.z, v3.w};
                us8 p0, p1;
#pragma unroll
                for (int i = 0; i < 8; ++i) { p0[i] = f2b(vals[i]); p1[i] = f2b(vals[8 + i]); }
                *(us8*)&sA[arow][akh]     = p0;
                *(us8*)&sA[arow][akh + 8] = p1;
            } else {
                *(float4*)&sA[arow][akh]     = make_float4(0.f, 0.f, 0.f, 0.f);
                *(float4*)&sA[arow][akh + 8] = make_float4(0.f, 0.f, 0.f, 0.f);
            }
        }
        // ---- stage B (both planes; contiguous k-blocked layout) ----
#pragma unroll
        for (int p = 0; p < 2; ++p) {
            const unsigned short* src = Wt + ((size_t)(p * KB + kb) * Nn + n0) * 32 + tid * 16;
            unsigned short* dst = &sB[p][0][0] + tid * 16;
            *(float4*)dst       = *(const float4*)src;
            *(float4*)(dst + 8) = *(const float4*)(src + 8);
        }
        __syncthreads();
        // ---- MFMA ----
        const bf16x8 a0 = *(const bf16x8*)&sA[w * 32 + fr][fq];
        const bf16x8 a1 = *(const bf16x8*)&sA[w * 32 + 16 + fr][fq];
#pragma unroll
        for (int c = 0; c < 8; ++c) {
            const bf16x8 bh = *(const bf16x8*)&sB[0][c * 16 + fr][fq];
            const bf16x8 bl = *(const bf16x8*)&sB[1][c * 16 + fr][fq];
            acc[0][c] = __builtin_amdgcn_mfma_f32_16x16x32_bf16(a0, bh, acc[0][c], 0, 0, 0);
            acc[0][c] = __builtin_amdgcn_mfma_f32_16x16x32_bf16(a0, bl, acc[0][c], 0, 0, 0);
            acc[1][c] = __builtin_amdgcn_mfma_f32_16x16x32_bf16(a1, bh, acc[1][c], 0, 0, 0);
            acc[1][c] = __builtin_amdgcn_mfma_f32_16x16x32_bf16(a1, bl, acc[1][c], 0, 0, 0);
        }
    }

    // ---- epilogue: C/D layout col=lane&15, row=(lane>>4)*4+reg ----
    float s[8], q[8];
#pragma unroll
    for (int c = 0; c < 8; ++c) { s[c] = 0.f; q[c] = 0.f; }
    const int crow4 = (lane >> 4) * 4;
#pragma unroll
    for (int r = 0; r < 2; ++r) {
        const int rbase = m0 + w * 32 + r * 16 + crow4;
#pragma unroll
        for (int c = 0; c < 8; ++c) {
            const int gc = n0 + c * 16 + fr;
            const float bb = bias[gc];
#pragma unroll
            for (int reg = 0; reg < 4; ++reg) {
                const int gr = rbase + reg;
                if (gr >= M) continue;
                float o = acc[r][c][reg] + bb;
                if (resid) o += resid[(size_t)gr * Nn + gc];
                if (relu) o = fmaxf(o, 0.f);
                if (stats) { s[c] += o; q[c] = fmaf(o, o, q[c]); }
                if (CBF) ((unsigned short*)Cp)[(size_t)gr * Nn + gc] = f2b(o);
                else     ((float*)Cp)[(size_t)gr * Nn + gc] = o;
            }
        }
    }

    if (stats) {
#pragma unroll
        for (int c = 0; c < 8; ++c) {
            s[c] += __shfl_xor(s[c], 32, 64); s[c] += __shfl_xor(s[c], 16, 64);
            q[c] += __shfl_xor(q[c], 32, 64); q[c] += __shfl_xor(q[c], 16, 64);
        }
        __syncthreads();
        float* red = (float*)sA;   // 1024 floats used of 2048
        if (lane < 16) {
#pragma unroll
            for (int c = 0; c < 8; ++c) {
                red[w * 128 + c * 16 + lane]       = s[c];
                red[512 + w * 128 + c * 16 + lane] = q[c];
            }
        }
        __syncthreads();
        if (tid < 128) {
            const float ss = red[tid] + red[128 + tid] + red[256 + tid] + red[384 + tid];
            const float qq = red[512 + tid] + red[640 + tid] + red[768 + tid] + red[896 + tid];
            atomicAdd(&stats[tid], ss);
            atomicAdd(&stats[Nn + tid], qq);
        }
    }
}

// ---------------------------------------------------------------------------
// fp32 tiled GEMM (input projection only, K=80). Also emits bf16 dup of C.
// ---------------------------------------------------------------------------
__global__ __launch_bounds__(256, 4)
void gemm_kernel(const float* __restrict__ A, const float* __restrict__ W,
                 const float* __restrict__ bias, float* __restrict__ C,
                 unsigned short* __restrict__ Cb, int M, int K, int Nn, int relu)
{
    __shared__ float aT[16][128];
    __shared__ float wsh[16][128];

    const int tid = threadIdx.x;
    const int m0 = blockIdx.x * 128;
    const int n0 = blockIdx.y * 128;
    const int rm = (tid >> 4) * 8;
    const int rn = (tid & 15) * 8;

    float acc[8][8];
#pragma unroll
    for (int i = 0; i < 8; ++i)
#pragma unroll
        for (int j = 0; j < 8; ++j) acc[i][j] = 0.f;

    const int lm = tid & 127;
    const int kq = (tid >> 7) * 8;
    const int wk = tid >> 4;
    const int wj = (tid & 15) * 8;

    for (int k0 = 0; k0 < K; k0 += 16) {
        {
            const int gm = m0 + lm;
            if (gm < M) {
                const float4 v0 = *(const float4*)&A[(size_t)gm * K + k0 + kq];
                const float4 v1 = *(const float4*)&A[(size_t)gm * K + k0 + kq + 4];
                aT[kq + 0][lm] = v0.x; aT[kq + 1][lm] = v0.y;
                aT[kq + 2][lm] = v0.z; aT[kq + 3][lm] = v0.w;
                aT[kq + 4][lm] = v1.x; aT[kq + 5][lm] = v1.y;
                aT[kq + 6][lm] = v1.z; aT[kq + 7][lm] = v1.w;
            } else {
#pragma unroll
                for (int i = 0; i < 8; ++i) aT[kq + i][lm] = 0.f;
            }
        }
        {
            const float4 w0 = *(const float4*)&W[(size_t)(k0 + wk) * Nn + n0 + wj];
            const float4 w1 = *(const float4*)&W[(size_t)(k0 + wk) * Nn + n0 + wj + 4];
            *(float4*)&wsh[wk][wj]     = w0;
            *(float4*)&wsh[wk][wj + 4] = w1;
        }
        __syncthreads();
#pragma unroll
        for (int k = 0; k < 16; ++k) {
            const float4 a0 = *(const float4*)&aT[k][rm];
            const float4 a1 = *(const float4*)&aT[k][rm + 4];
            const float4 b0 = *(const float4*)&wsh[k][rn];
            const float4 b1 = *(const float4*)&wsh[k][rn + 4];
            const float av[8] = {a0.x, a0.y, a0.z, a0.w, a1.x, a1.y, a1.z, a1.w};
            const float bv[8] = {b0.x, b0.y, b0.z, b0.w, b1.x, b1.y, b1.z, b1.w};
#pragma unroll
            for (int i = 0; i < 8; ++i)
#pragma unroll
                for (int j = 0; j < 8; ++j)
                    acc[i][j] = fmaf(av[i], bv[j], acc[i][j]);
        }
        __syncthreads();
    }

    float bv[8];
#pragma unroll
    for (int j = 0; j < 8; ++j) bv[j] = bias[n0 + rn + j];
#pragma unroll
    for (int i = 0; i < 8; ++i) {
        const int gm = m0 + rm + i;
        if (gm >= M) continue;
        float o[8];
#pragma unroll
        for (int j = 0; j < 8; ++j) {
            o[j] = acc[i][j] + bv[j];
            if (relu) o[j] = fmaxf(o[j], 0.f);
        }
        *(float4*)&C[(size_t)gm * Nn + n0 + rn]     = make_float4(o[0], o[1], o[2], o[3]);
        *(float4*)&C[(size_t)gm * Nn + n0 + rn + 4] = make_float4(o[4], o[5], o[6], o[7]);
        if (Cb) {
            us8 pk;
#pragma unroll
            for (int j = 0; j < 8; ++j) pk[j] = f2b(o[j]);
            *(us8*)&Cb[(size_t)gm * Nn + n0 + rn] = pk;
        }
    }
}

// ---------------------------------------------------------------------------
// CSR build
// ---------------------------------------------------------------------------
__global__ void hist_kernel(const int* __restrict__ ei, int* __restrict__ deg)
{
    const int e = blockIdx.x * 256 + threadIdx.x;
    if (e < NE) atomicAdd(&deg[ei[NE + e]], 1);
}

__global__ __launch_bounds__(1024)
void scan_kernel(const int* __restrict__ deg, int* __restrict__ rowptr,
                 int* __restrict__ cursor)
{
    __shared__ int part[1024];
    const int tid = threadIdx.x;
    const int c0 = tid * 49;
    const int c1 = min(c0 + 49, NN);
    int sum = 0;
    for (int i = c0; i < c1; ++i) sum += deg[i];
    part[tid] = sum;
    __syncthreads();
    for (int off = 1; off < 1024; off <<= 1) {
        const int v = (tid >= off) ? part[tid - off] : 0;
        __syncthreads();
        part[tid] += v;
        __syncthreads();
    }
    int base = (tid == 0) ? 0 : part[tid - 1];
    for (int i = c0; i < c1; ++i) {
        rowptr[i] = base;
        cursor[i] = base;
        base += deg[i];
    }
    if (tid == 1023) rowptr[NN] = part[1023];
}

__global__ void scatter_kernel(const int* __restrict__ ei, const float* __restrict__ ea,
                               int* __restrict__ cursor, int* __restrict__ src_s,
                               float* __restrict__ ea_s)
{
    const int e = blockIdx.x * 256 + threadIdx.x;
    if (e >= NE) return;
    const int d = ei[NE + e];
    const int pos = atomicAdd(&cursor[d], 1);
    src_s[pos] = ei[e];
    const float4* sp = (const float4*)&ea[(size_t)e * 16];
    float4* dp = (float4*)&ea_s[(size_t)pos * 16];
    dp[0] = sp[0]; dp[1] = sp[1]; dp[2] = sp[2]; dp[3] = sp[3];
}

// ---------------------------------------------------------------------------
// Aggregation: z = (1+eps)*h + sum relu(h[src] + ea@We + be). One wave/node.
// Gathers h rows from the bf16 copy (256 B rows); batches 4 gathers/chunk.
// ---------------------------------------------------------------------------
__global__ __launch_bounds__(256)
void agg_kernel(const float* __restrict__ h, const unsigned short* __restrict__ hb,
                const int* __restrict__ rowptr, const int* __restrict__ src_s,
                const float* __restrict__ ea_s, const float* __restrict__ We,
                const float* __restrict__ be, const float* __restrict__ eps, int l,
                float* __restrict__ z)
{
    const int lane = threadIdx.x & 63;
    const int w = threadIdx.x >> 6;
    const int n = blockIdx.x * 4 + w;
    if (n >= NN) return;

    float w0[16], w1[16];
#pragma unroll
    for (int k = 0; k < 16; ++k) {
        const float2 wv = *(const float2*)&We[k * H + 2 * lane];
        w0[k] = wv.x; w1[k] = wv.y;
    }
    const float2 bev = *(const float2*)&be[2 * lane];

    int beg = __builtin_amdgcn_readfirstlane(rowptr[n]);
    int end = __builtin_amdgcn_readfirstlane(rowptr[n + 1]);

    const float e1 = 1.0f + eps[l];
    const float2 hv0 = *(const float2*)&h[(size_t)n * H + 2 * lane];
    float acc0 = e1 * hv0.x;
    float acc1 = e1 * hv0.y;

    for (int i0 = beg; i0 < end; i0 += 4) {
        const int idx = min(i0 * 16 + lane, NE * 16 - 1);
        const float xv = ea_s[idx];
        const int jn = min(4, end - i0);
        int srcs[4];
#pragma unroll
        for (int j = 0; j < 4; ++j)
            srcs[j] = __builtin_amdgcn_readfirstlane(src_s[(j < jn) ? (i0 + j) : i0]);
        float2 hvv[4];
#pragma unroll
        for (int j = 0; j < 4; ++j) {
            const unsigned int hraw = *(const unsigned int*)&hb[(size_t)srcs[j] * H + 2 * lane];
            hvv[j] = make_float2(b2f((unsigned short)(hraw & 0xffff)),
                                 b2f((unsigned short)(hraw >> 16)));
        }
#pragma unroll
        for (int j = 0; j < 4; ++j) {
            if (j >= jn) break;
            float s0 = bev.x, s1 = bev.y;
#pragma unroll
            for (int k = 0; k < 16; ++k) {
                const float a = __shfl(xv, j * 16 + k, 64);
                s0 = fmaf(a, w0[k], s0);
                s1 = fmaf(a, w1[k], s1);
            }
            acc0 += fmaxf(hvv[j].x + s0, 0.f);
            acc1 += fmaxf(hvv[j].y + s1, 0.f);
        }
    }
    *(float2*)&z[(size_t)n * H + 2 * lane] = make_float2(acc0, acc1);
}

// ---------------------------------------------------------------------------
// Elementwise / BN / pool / readout
// ---------------------------------------------------------------------------
__global__ void concat_kernel(const float* __restrict__ x, const float* __restrict__ pe,
                              float* __restrict__ xin)
{
    const int i = blockIdx.x * 256 + threadIdx.x;
    const int row = i / FIN;
    const int c = i - row * FIN;
    xin[i] = (c < 64) ? x[row * 64 + c] : pe[row * 16 + (c - 64)];
}

__global__ void post_gin_kernel(const float* __restrict__ t, const float* __restrict__ h,
                                const float* __restrict__ ab, float* __restrict__ zin)
{
    const int i = blockIdx.x * 256 + threadIdx.x;
    const int c = i & (H - 1);
    zin[i] = fmaxf(fmaf(t[i], ab[c], ab[H + c]), 0.f) + h[i];
}

__global__ void bn_apply_kernel(const float* __restrict__ u, const float* __restrict__ ab,
                                float* __restrict__ h, unsigned short* __restrict__ hb)
{
    const int i = blockIdx.x * 256 + threadIdx.x;
    const int c = i & (H - 1);
    const float v = fmaf(u[i], ab[c], ab[H + c]);
    h[i] = v;
    hb[i] = f2b(v);
}

__global__ void bn_finalize_kernel(const float* __restrict__ stats, const float* __restrict__ g,
                                   const float* __restrict__ b, float* __restrict__ ab,
                                   float inv_n)
{
    const int c = threadIdx.x;
    const float mean = stats[c] * inv_n;
    const float var = stats[H + c] * inv_n - mean * mean;
    const float a = g[c] * rsqrtf(var + BN_EPS);
    ab[c] = a;
    ab[H + c] = fmaf(-mean, a, b[c]);
}

__global__ void pool_kernel(const float* __restrict__ h, const int* __restrict__ batch,
                            float* __restrict__ pool, float* __restrict__ cnt, int n)
{
    const int c = threadIdx.x & (H - 1);
    const int half = threadIdx.x >> 7;
    const int r0 = blockIdx.x * 256 + half * 128;
    if (r0 >= n) return;
    const int rend = min(r0 + 128, n);
    int gprev = batch[r0];
    float acc = 0.f;
    int run = 0;
    for (int r = r0; r < rend; ++r) {
        const int g = batch[r];
        if (g != gprev) {
            atomicAdd(&pool[gprev * H + c], acc);
            if (c == 0) atomicAdd(&cnt[gprev], (float)run);
            acc = 0.f; run = 0; gprev = g;
        }
        acc += h[(size_t)r * H + c];
        run++;
    }
    atomicAdd(&pool[gprev * H + c], acc);
    if (c == 0) atomicAdd(&cnt[gprev], (float)run);
}

__global__ void readout_kernel(const float* __restrict__ pool, const float* __restrict__ cnt,
                               const float* __restrict__ Wr1, const float* __restrict__ br1,
                               const float* __restrict__ Wr2, const float* __restrict__ br2,
                               float* __restrict__ out)
{
    __shared__ float hg[H];
    __shared__ float r1[H];
    const int g = blockIdx.x;
    const int j = threadIdx.x;
    hg[j] = pool[g * H + j] / fmaxf(cnt[g], 1.0f);
    __syncthreads();
    float acc = br1[j];
    for (int k = 0; k < H; ++k) acc = fmaf(hg[k], Wr1[k * H + j], acc);
    r1[j] = fmaxf(acc, 0.f);
    __syncthreads();
    if (j < NCLS) {
        float o = br2[j];
        for (int k = 0; k < H; ++k) o = fmaf(r1[k], Wr2[k * NCLS + j], o);
        out[g * NCLS + j] = o;
    }
}

// ---------------------------------------------------------------------------
extern "C" void kernel_launch(void* const* d_in, const int* in_sizes, int n_in,
                              void* d_out, int out_size, void* d_ws, size_t ws_size,
                              hipStream_t stream)
{
    const float* x       = (const float*)d_in[0];
    const float* pe      = (const float*)d_in[1];
    const int*   ei      = (const int*)d_in[2];
    const float* ea      = (const float*)d_in[3];
    const int*   batch   = (const int*)d_in[4];
    const float* W_in    = (const float*)d_in[5];
    const float* b_in    = (const float*)d_in[6];
    const float* We_edge = (const float*)d_in[7];
    const float* be_edge = (const float*)d_in[8];
    const float* eps     = (const float*)d_in[9];
    const float* W1g     = (const float*)d_in[10];
    const float* b1g     = (const float*)d_in[11];
    const float* W2g     = (const float*)d_in[12];
    const float* b2g     = (const float*)d_in[13];
    const float* bn1g    = (const float*)d_in[14];
    const float* bn1b    = (const float*)d_in[15];
    const float* W1f     = (const float*)d_in[16];
    const float* b1f     = (const float*)d_in[17];
    const float* W2f     = (const float*)d_in[18];
    const float* b2f     = (const float*)d_in[19];
    const float* bn2g    = (const float*)d_in[20];
    const float* bn2b    = (const float*)d_in[21];
    const float* Wr1     = (const float*)d_in[22];
    const float* br1     = (const float*)d_in[23];
    const float* Wr2     = (const float*)d_in[24];
    const float* br2     = (const float*)d_in[25];
    float* out = (float*)d_out;

    const size_t NH = (size_t)NN * H;
    float* hbuf  = (float*)d_ws;                     // [NN,H] fp32
    float* zbuf  = hbuf + NH;                        // [NN,H] fp32
    float* tbuf  = zbuf + NH;                        // [NN,H] fp32
    unsigned short* z1 = (unsigned short*)(tbuf + NH);        // [NN,H2] bf16 (also xin fp32 scratch)
    float* stats = (float*)(z1 + (size_t)NN * H2);   // [4*H]
    float* bnp   = stats + 4 * H;                    // [4*H]
    float* pool  = bnp + 4 * H;                      // [NG,H]
    float* cnt   = pool + NG * H;                    // [NG]
    int*   rowptr = (int*)(cnt + NG);                // [NN+1]
    int*   cursor = rowptr + NN + 1;                 // [NN]
    int*   deg    = cursor + NN;                     // [NN]
    int*   src_s  = deg + NN;                        // [NE]
    float* ea_s   = (float*)(src_s + NE);            // [NE,16]
    unsigned short* hb = (unsigned short*)(ea_s + (size_t)NE * 16);  // [NN,H] bf16
    unsigned short* wt = hb + NH;                    // 16 matrices x 2*K*N = 16*65536
    unsigned short* wt1g = wt;
    unsigned short* wt2g = wt + 4 * 65536;
    unsigned short* wt1f = wt + 8 * 65536;
    unsigned short* wt2f = wt + 12 * 65536;

    const dim3 blk(256);
    const dim3 mg1((NN + 127) / 128, 1);
    const dim3 mg2((NN + 127) / 128, 2);
    const int ew_grid = (int)(NH / 256);
    const float inv_n = 1.0f / (float)NN;

    // ---- weight prep (hi/lo split, k-blocked transpose) ----
    wprep_kernel<<<512, blk, 0, stream>>>(W1g, wt1g, 128, 256);
    wprep_kernel<<<512, blk, 0, stream>>>(W2g, wt2g, 256, 128);
    wprep_kernel<<<512, blk, 0, stream>>>(W1f, wt1f, 128, 256);
    wprep_kernel<<<512, blk, 0, stream>>>(W2f, wt2f, 256, 128);

    // ---- CSR build ----
    hipMemsetAsync(deg, 0, NN * sizeof(int), stream);
    hist_kernel<<<(NE + 255) / 256, blk, 0, stream>>>(ei, deg);
    scan_kernel<<<1, 1024, 0, stream>>>(deg, rowptr, cursor);
    scatter_kernel<<<(NE + 255) / 256, blk, 0, stream>>>(ei, ea, cursor, src_s, ea_s);

    // ---- input projection ----
    concat_kernel<<<(NN * FIN) / 256, blk, 0, stream>>>(x, pe, (float*)z1);
    gemm_kernel<<<mg1, blk, 0, stream>>>((float*)z1, W_in, b_in, hbuf, hb, NN, FIN, H, 1);

    for (int l = 0; l < 4; ++l) {
        hipMemsetAsync(stats, 0, 4 * H * sizeof(float), stream);

        agg_kernel<<<(NN + 3) / 4, blk, 0, stream>>>(hbuf, hb, rowptr, src_s, ea_s,
                                                     We_edge + (size_t)l * 16 * H,
                                                     be_edge + (size_t)l * H, eps, l, zbuf);

        // GIN MLP
        mgemm<false, true><<<mg2, blk, 0, stream>>>(zbuf, wt1g + (size_t)l * 65536,
                                                    b1g + (size_t)l * H2, nullptr, z1,
                                                    NN, 128, 256, 1, nullptr);
        mgemm<true, false><<<mg1, blk, 0, stream>>>(z1, wt2g + (size_t)l * 65536,
                                                    b2g + (size_t)l * H, nullptr, tbuf,
                                                    NN, 256, 128, 0, stats);
        bn_finalize_kernel<<<1, H, 0, stream>>>(stats, bn1g + (size_t)l * H,
                                                bn1b + (size_t)l * H, bnp, inv_n);
        post_gin_kernel<<<ew_grid, blk, 0, stream>>>(tbuf, hbuf, bnp, zbuf);

        // FFN
        mgemm<false, true><<<mg2, blk, 0, stream>>>(zbuf, wt1f + (size_t)l * 65536,
                                                    b1f + (size_t)l * H2, nullptr, z1,
                                                    NN, 128, 256, 1, nullptr);
        mgemm<true, false><<<mg1, blk, 0, stream>>>(z1, wt2f + (size_t)l * 65536,
                                                    b2f + (size_t)l * H, zbuf, tbuf,
                                                    NN, 256, 128, 0, stats + 2 * H);
        bn_finalize_kernel<<<1, H, 0, stream>>>(stats + 2 * H, bn2g + (size_t)l * H,
                                                bn2b + (size_t)l * H, bnp + 2 * H, inv_n);
        bn_apply_kernel<<<ew_grid, blk, 0, stream>>>(tbuf, bnp + 2 * H, hbuf, hb);
    }

    hipMemsetAsync(pool, 0, (NG * H + NG) * sizeof(float), stream);
    pool_kernel<<<(NN + 255) / 256, blk, 0, stream>>>(hbuf, batch, pool, cnt, NN);
    readout_kernel<<<NG, H, 0, stream>>>(pool, cnt, Wr1, br1, Wr2, br2, out);
}

// Round 4
// 1427.083 us; speedup vs baseline: 2.2973x; 1.1567x over previous
//
#include <hip/hip_runtime.h>
#include <hip/hip_bf16.h>

#define NN 50000
#define NE 800000
#define FIN 80
#define H 128
#define H2 256
#define NG 64
#define NCLS 10
#define BN_EPS 1e-5f

typedef __attribute__((ext_vector_type(8))) short bf16x8;
typedef __attribute__((ext_vector_type(8))) unsigned short us8;
typedef __attribute__((ext_vector_type(4))) float f32x4;

__device__ __forceinline__ unsigned short f2b(float f) {
    __hip_bfloat16 h = __float2bfloat16(f);   // RNE
    return *(unsigned short*)&h;
}
__device__ __forceinline__ float b2f(unsigned short u) {
    unsigned v = (unsigned)u << 16;
    return __uint_as_float(v);
}

// ---------------------------------------------------------------------------
// Weight prep: W[L][K][Nn] fp32 -> per-layer {hi,lo} bf16 planes, k-blocked:
// dst[l][ ((p*KB + kb)*Nn + n)*32 + kk ]
// ---------------------------------------------------------------------------
__global__ void wprep_kernel(const float* __restrict__ W, unsigned short* __restrict__ Wt,
                             int K, int Nn)
{
    const int idx = blockIdx.x * 256 + threadIdx.x;
    const int per = K * Nn;
    const int l = idx / per;
    const int r = idx - l * per;
    const int k = r / Nn;
    const int n = r - k * Nn;
    const float wv = W[idx];
    const unsigned short hi = f2b(wv);
    const unsigned short lo = f2b(wv - b2f(hi));
    const int KB = K >> 5;
    const int kb = k >> 5, kk = k & 31;
    unsigned short* base = Wt + (size_t)l * 2 * per;
    base[((size_t)(0 * KB + kb) * Nn + n) * 32 + kk] = hi;
    base[((size_t)(1 * KB + kb) * Nn + n) * 32 + kk] = lo;
}

// ---------------------------------------------------------------------------
// MFMA GEMM: C[M,Nn] = act(A[M,K] @ (Whi+Wlo) + bias (+resid))
// BM=128, BN=128 (grid.y tiles Nn), BK=32, 256 thr = 4 waves, 16x16x32 bf16.
// ABF: A bf16; else fp32 converted in staging.
// CBF: C bf16; else fp32.
// statsOut: fused per-column sum/sumsq (Nn==128 only).
// ZF: A-staging computes z = relu(bn1(t)) + h from (Ap=t, hres, statsIn,
//     bng, bnb) and writes z to zout (from blockIdx.y==0 blocks only).
// ---------------------------------------------------------------------------
template<bool ABF, bool CBF, bool ZF>
__global__ __launch_bounds__(256, 2)
void mgemm(const void* __restrict__ Ap, const unsigned short* __restrict__ Wt,
           const float* __restrict__ bias, const float* __restrict__ resid,
           void* __restrict__ Cp, int M, int K, int Nn, int relu,
           float* __restrict__ statsOut,
           const float* __restrict__ statsIn, const float* __restrict__ bng,
           const float* __restrict__ bnb, const float* __restrict__ hres,
           float* __restrict__ zout, float inv_n)
{
    __shared__ unsigned short sA[128][32];      // A[m][k]   8 KB
    __shared__ unsigned short sB[2][128][32];   // Bt[p][n][k] 16 KB
    __shared__ float sAB[128];                  // bn scale (ZF)
    __shared__ float sSH[128];                  // bn shift (ZF)

    const int tid = threadIdx.x;
    const int m0 = blockIdx.x * 128;
    const int n0 = blockIdx.y * 128;
    const int lane = tid & 63;
    const int w = tid >> 6;
    const int KB = K >> 5;

    if (ZF) {
        if (tid < 128) {
            const float mean = statsIn[tid] * inv_n;
            const float var = statsIn[128 + tid] * inv_n - mean * mean;
            const float a = bng[tid] * rsqrtf(var + BN_EPS);
            sAB[tid] = a;
            sSH[tid] = fmaf(-mean, a, bnb[tid]);
        }
    }

    f32x4 acc[2][8];
#pragma unroll
    for (int r = 0; r < 2; ++r)
#pragma unroll
        for (int c = 0; c < 8; ++c) acc[r][c] = (f32x4)(0.f);

    const int arow = tid >> 1;
    const int akh = (tid & 1) * 16;
    const int gm = m0 + arow;
    const int fr = lane & 15;
    const int fq = (lane >> 4) * 8;

    for (int kb = 0; kb < KB; ++kb) {
        const int k0 = kb * 32;
        __syncthreads();
        // ---- stage A ----
        if (ABF) {
            if (gm < M) {
                const unsigned short* Ab = (const unsigned short*)Ap + (size_t)gm * K + k0 + akh;
                *(float4*)&sA[arow][akh]     = *(const float4*)Ab;
                *(float4*)&sA[arow][akh + 8] = *(const float4*)(Ab + 8);
            } else {
                *(float4*)&sA[arow][akh]     = make_float4(0.f, 0.f, 0.f, 0.f);
                *(float4*)&sA[arow][akh + 8] = make_float4(0.f, 0.f, 0.f, 0.f);
            }
        } else if (ZF) {
            if (gm < M) {
                const float* tf = (const float*)Ap + (size_t)gm * K + k0 + akh;
                const float* hf = hres + (size_t)gm * K + k0 + akh;
                float zv[16];
#pragma unroll
                for (int i = 0; i < 16; ++i) {
                    const int c = k0 + akh + i;
                    zv[i] = fmaxf(fmaf(tf[i], sAB[c], sSH[c]), 0.f) + hf[i];
                }
                if (blockIdx.y == 0) {
                    float* zo = zout + (size_t)gm * K + k0 + akh;
#pragma unroll
                    for (int i = 0; i < 16; i += 4)
                        *(float4*)(zo + i) = make_float4(zv[i], zv[i + 1], zv[i + 2], zv[i + 3]);
                }
                us8 p0, p1;
#pragma unroll
                for (int i = 0; i < 8; ++i) { p0[i] = f2b(zv[i]); p1[i] = f2b(zv[8 + i]); }
                *(us8*)&sA[arow][akh]     = p0;
                *(us8*)&sA[arow][akh + 8] = p1;
            } else {
                *(float4*)&sA[arow][akh]     = make_float4(0.f, 0.f, 0.f, 0.f);
                *(float4*)&sA[arow][akh + 8] = make_float4(0.f, 0.f, 0.f, 0.f);
            }
        } else {
            if (gm < M) {
                const float* Af = (const float*)Ap + (size_t)gm * K + k0 + akh;
                const float4 v0 = *(const float4*)(Af);
                const float4 v1 = *(const float4*)(Af + 4);
                const float4 v2 = *(const float4*)(Af + 8);
                const float4 v3 = *(const float4*)(Af + 12);
                const float vals[16] = {v0.x, v0.y, v0.z, v0.w, v1.x, v1.y, v1.z, v1.w,
                                        v2.x, v2.y, v2.z, v2.w, v3.x, v3.y, v3.z, v3.w};
                us8 p0, p1;
#pragma unroll
                for (int i = 0; i < 8; ++i) { p0[i] = f2b(vals[i]); p1[i] = f2b(vals[8 + i]); }
                *(us8*)&sA[arow][akh]     = p0;
                *(us8*)&sA[arow][akh + 8] = p1;
            } else {
                *(float4*)&sA[arow][akh]     = make_float4(0.f, 0.f, 0.f, 0.f);
                *(float4*)&sA[arow][akh + 8] = make_float4(0.f, 0.f, 0.f, 0.f);
            }
        }
        // ---- stage B ----
#pragma unroll
        for (int p = 0; p < 2; ++p) {
            const unsigned short* src = Wt + ((size_t)(p * KB + kb) * Nn + n0) * 32 + tid * 16;
            unsigned short* dst = &sB[p][0][0] + tid * 16;
            *(float4*)dst       = *(const float4*)src;
            *(float4*)(dst + 8) = *(const float4*)(src + 8);
        }
        __syncthreads();
        // ---- MFMA ----
        const bf16x8 a0 = *(const bf16x8*)&sA[w * 32 + fr][fq];
        const bf16x8 a1 = *(const bf16x8*)&sA[w * 32 + 16 + fr][fq];
#pragma unroll
        for (int c = 0; c < 8; ++c) {
            const bf16x8 bh = *(const bf16x8*)&sB[0][c * 16 + fr][fq];
            const bf16x8 bl = *(const bf16x8*)&sB[1][c * 16 + fr][fq];
            acc[0][c] = __builtin_amdgcn_mfma_f32_16x16x32_bf16(a0, bh, acc[0][c], 0, 0, 0);
            acc[0][c] = __builtin_amdgcn_mfma_f32_16x16x32_bf16(a0, bl, acc[0][c], 0, 0, 0);
            acc[1][c] = __builtin_amdgcn_mfma_f32_16x16x32_bf16(a1, bh, acc[1][c], 0, 0, 0);
            acc[1][c] = __builtin_amdgcn_mfma_f32_16x16x32_bf16(a1, bl, acc[1][c], 0, 0, 0);
        }
    }

    // ---- epilogue: C/D layout col=lane&15, row=(lane>>4)*4+reg ----
    float s[8], q[8];
#pragma unroll
    for (int c = 0; c < 8; ++c) { s[c] = 0.f; q[c] = 0.f; }
    const int crow4 = (lane >> 4) * 4;
#pragma unroll
    for (int r = 0; r < 2; ++r) {
        const int rbase = m0 + w * 32 + r * 16 + crow4;
#pragma unroll
        for (int c = 0; c < 8; ++c) {
            const int gc = n0 + c * 16 + fr;
            const float bb = bias[gc];
#pragma unroll
            for (int reg = 0; reg < 4; ++reg) {
                const int gr = rbase + reg;
                if (gr >= M) continue;
                float o = acc[r][c][reg] + bb;
                if (resid) o += resid[(size_t)gr * Nn + gc];
                if (relu) o = fmaxf(o, 0.f);
                if (statsOut) { s[c] += o; q[c] = fmaf(o, o, q[c]); }
                if (CBF) ((unsigned short*)Cp)[(size_t)gr * Nn + gc] = f2b(o);
                else     ((float*)Cp)[(size_t)gr * Nn + gc] = o;
            }
        }
    }

    if (statsOut) {
#pragma unroll
        for (int c = 0; c < 8; ++c) {
            s[c] += __shfl_xor(s[c], 32, 64); s[c] += __shfl_xor(s[c], 16, 64);
            q[c] += __shfl_xor(q[c], 32, 64); q[c] += __shfl_xor(q[c], 16, 64);
        }
        __syncthreads();
        float* red = (float*)sA;
        if (lane < 16) {
#pragma unroll
            for (int c = 0; c < 8; ++c) {
                red[w * 128 + c * 16 + lane]       = s[c];
                red[512 + w * 128 + c * 16 + lane] = q[c];
            }
        }
        __syncthreads();
        if (tid < 128) {
            const float ss = red[tid] + red[128 + tid] + red[256 + tid] + red[384 + tid];
            const float qq = red[512 + tid] + red[640 + tid] + red[768 + tid] + red[896 + tid];
            atomicAdd(&statsOut[tid], ss);
            atomicAdd(&statsOut[128 + tid], qq);
        }
    }
}

// ---------------------------------------------------------------------------
// fp32 tiled GEMM (input projection only, K=80). Also emits bf16 dup of C.
// ---------------------------------------------------------------------------
__global__ __launch_bounds__(256, 4)
void gemm_kernel(const float* __restrict__ A, const float* __restrict__ W,
                 const float* __restrict__ bias, float* __restrict__ C,
                 unsigned short* __restrict__ Cb, int M, int K, int Nn, int relu)
{
    __shared__ float aT[16][128];
    __shared__ float wsh[16][128];

    const int tid = threadIdx.x;
    const int m0 = blockIdx.x * 128;
    const int n0 = blockIdx.y * 128;
    const int rm = (tid >> 4) * 8;
    const int rn = (tid & 15) * 8;

    float acc[8][8];
#pragma unroll
    for (int i = 0; i < 8; ++i)
#pragma unroll
        for (int j = 0; j < 8; ++j) acc[i][j] = 0.f;

    const int lm = tid & 127;
    const int kq = (tid >> 7) * 8;
    const int wk = tid >> 4;
    const int wj = (tid & 15) * 8;

    for (int k0 = 0; k0 < K; k0 += 16) {
        {
            const int gm = m0 + lm;
            if (gm < M) {
                const float4 v0 = *(const float4*)&A[(size_t)gm * K + k0 + kq];
                const float4 v1 = *(const float4*)&A[(size_t)gm * K + k0 + kq + 4];
                aT[kq + 0][lm] = v0.x; aT[kq + 1][lm] = v0.y;
                aT[kq + 2][lm] = v0.z; aT[kq + 3][lm] = v0.w;
                aT[kq + 4][lm] = v1.x; aT[kq + 5][lm] = v1.y;
                aT[kq + 6][lm] = v1.z; aT[kq + 7][lm] = v1.w;
            } else {
#pragma unroll
                for (int i = 0; i < 8; ++i) aT[kq + i][lm] = 0.f;
            }
        }
        {
            const float4 w0 = *(const float4*)&W[(size_t)(k0 + wk) * Nn + n0 + wj];
            const float4 w1 = *(const float4*)&W[(size_t)(k0 + wk) * Nn + n0 + wj + 4];
            *(float4*)&wsh[wk][wj]     = w0;
            *(float4*)&wsh[wk][wj + 4] = w1;
        }
        __syncthreads();
#pragma unroll
        for (int k = 0; k < 16; ++k) {
            const float4 a0 = *(const float4*)&aT[k][rm];
            const float4 a1 = *(const float4*)&aT[k][rm + 4];
            const float4 b0 = *(const float4*)&wsh[k][rn];
            const float4 b1 = *(const float4*)&wsh[k][rn + 4];
            const float av[8] = {a0.x, a0.y, a0.z, a0.w, a1.x, a1.y, a1.z, a1.w};
            const float bv[8] = {b0.x, b0.y, b0.z, b0.w, b1.x, b1.y, b1.z, b1.w};
#pragma unroll
            for (int i = 0; i < 8; ++i)
#pragma unroll
                for (int j = 0; j < 8; ++j)
                    acc[i][j] = fmaf(av[i], bv[j], acc[i][j]);
        }
        __syncthreads();
    }

    float bv[8];
#pragma unroll
    for (int j = 0; j < 8; ++j) bv[j] = bias[n0 + rn + j];
#pragma unroll
    for (int i = 0; i < 8; ++i) {
        const int gm = m0 + rm + i;
        if (gm >= M) continue;
        float o[8];
#pragma unroll
        for (int j = 0; j < 8; ++j) {
            o[j] = acc[i][j] + bv[j];
            if (relu) o[j] = fmaxf(o[j], 0.f);
        }
        *(float4*)&C[(size_t)gm * Nn + n0 + rn]     = make_float4(o[0], o[1], o[2], o[3]);
        *(float4*)&C[(size_t)gm * Nn + n0 + rn + 4] = make_float4(o[4], o[5], o[6], o[7]);
        if (Cb) {
            us8 pk;
#pragma unroll
            for (int j = 0; j < 8; ++j) pk[j] = f2b(o[j]);
            *(us8*)&Cb[(size_t)gm * Nn + n0 + rn] = pk;
        }
    }
}

// ---------------------------------------------------------------------------
// CSR build
// ---------------------------------------------------------------------------
__global__ void hist_kernel(const int* __restrict__ ei, int* __restrict__ deg)
{
    const int e = blockIdx.x * 256 + threadIdx.x;
    if (e < NE) atomicAdd(&deg[ei[NE + e]], 1);
}

__global__ __launch_bounds__(1024)
void scan_kernel(const int* __restrict__ deg, int* __restrict__ rowptr,
                 int* __restrict__ cursor)
{
    __shared__ int part[1024];
    const int tid = threadIdx.x;
    const int c0 = tid * 49;
    const int c1 = min(c0 + 49, NN);
    int sum = 0;
    for (int i = c0; i < c1; ++i) sum += deg[i];
    part[tid] = sum;
    __syncthreads();
    for (int off = 1; off < 1024; off <<= 1) {
        const int v = (tid >= off) ? part[tid - off] : 0;
        __syncthreads();
        part[tid] += v;
        __syncthreads();
    }
    int base = (tid == 0) ? 0 : part[tid - 1];
    for (int i = c0; i < c1; ++i) {
        rowptr[i] = base;
        cursor[i] = base;
        base += deg[i];
    }
    if (tid == 1023) rowptr[NN] = part[1023];
}

__global__ void scatter_kernel(const int* __restrict__ ei, const float* __restrict__ ea,
                               int* __restrict__ cursor, int* __restrict__ src_s,
                               float* __restrict__ ea_s)
{
    const int e = blockIdx.x * 256 + threadIdx.x;
    if (e >= NE) return;
    const int d = ei[NE + e];
    const int pos = atomicAdd(&cursor[d], 1);
    src_s[pos] = ei[e];
    const float4* sp = (const float4*)&ea[(size_t)e * 16];
    float4* dp = (float4*)&ea_s[(size_t)pos * 16];
    dp[0] = sp[0]; dp[1] = sp[1]; dp[2] = sp[2]; dp[3] = sp[3];
}

// ---------------------------------------------------------------------------
// Aggregation: z = (1+eps)*h + sum relu(h[src] + ea@We + be). One wave/node.
// ea + src_s read via wave-uniform scalar loads (no shuffles); gathers from
// bf16 h copy, 8 rows in flight.
// ---------------------------------------------------------------------------
__global__ __launch_bounds__(256)
void agg_kernel(const float* __restrict__ h, const unsigned short* __restrict__ hb,
                const int* __restrict__ rowptr, const int* __restrict__ src_s,
                const float* __restrict__ ea_s, const float* __restrict__ We,
                const float* __restrict__ be, const float* __restrict__ eps, int l,
                float* __restrict__ z)
{
    const int lane = threadIdx.x & 63;
    const int w = threadIdx.x >> 6;
    const int n = blockIdx.x * 4 + w;
    if (n >= NN) return;

    float w0[16], w1[16];
#pragma unroll
    for (int k = 0; k < 16; ++k) {
        const float2 wv = *(const float2*)&We[k * H + 2 * lane];
        w0[k] = wv.x; w1[k] = wv.y;
    }
    const float2 bev = *(const float2*)&be[2 * lane];

    const int beg = __builtin_amdgcn_readfirstlane(rowptr[n]);
    const int end = __builtin_amdgcn_readfirstlane(rowptr[n + 1]);

    const float e1 = 1.0f + eps[l];
    const float2 hv0 = *(const float2*)&h[(size_t)n * H + 2 * lane];
    float acc0 = e1 * hv0.x;
    float acc1 = e1 * hv0.y;

    for (int i0 = beg; i0 < end; i0 += 8) {
        const int jn = min(8, end - i0);
        int srcs[8];
#pragma unroll
        for (int j = 0; j < 8; ++j)
            srcs[j] = src_s[(i0 + j < end) ? (i0 + j) : (end - 1)];
        unsigned hraw[8];
#pragma unroll
        for (int j = 0; j < 8; ++j)
            hraw[j] = *(const unsigned*)&hb[(size_t)srcs[j] * H + 2 * lane];
#pragma unroll
        for (int j = 0; j < 8; ++j) {
            if (j >= jn) break;
            const float* ar = ea_s + (size_t)(i0 + j) * 16;
            float s0 = bev.x, s1 = bev.y;
#pragma unroll
            for (int k = 0; k < 16; ++k) {
                const float a = ar[k];
                s0 = fmaf(a, w0[k], s0);
                s1 = fmaf(a, w1[k], s1);
            }
            const float hx = __uint_as_float(hraw[j] << 16);
            const float hy = __uint_as_float(hraw[j] & 0xffff0000u);
            acc0 += fmaxf(hx + s0, 0.f);
            acc1 += fmaxf(hy + s1, 0.f);
        }
    }
    *(float2*)&z[(size_t)n * H + 2 * lane] = make_float2(acc0, acc1);
}

// ---------------------------------------------------------------------------
// Elementwise / pool / readout
// ---------------------------------------------------------------------------
__global__ void concat_kernel(const float* __restrict__ x, const float* __restrict__ pe,
                              float* __restrict__ xin)
{
    const int i = blockIdx.x * 256 + threadIdx.x;
    const int row = i / FIN;
    const int c = i - row * FIN;
    xin[i] = (c < 64) ? x[row * 64 + c] : pe[row * 16 + (c - 64)];
}

// h = bn2(u); bn params computed inline from stats slab
__global__ void bn_apply_kernel(const float* __restrict__ u, const float* __restrict__ st,
                                const float* __restrict__ g, const float* __restrict__ b,
                                float* __restrict__ h, unsigned short* __restrict__ hb,
                                float inv_n)
{
    const int i = blockIdx.x * 256 + threadIdx.x;
    const int c = i & (H - 1);
    const float mean = st[c] * inv_n;
    const float var = st[H + c] * inv_n - mean * mean;
    const float a = g[c] * rsqrtf(var + BN_EPS);
    const float s = fmaf(-mean, a, b[c]);
    const float v = fmaf(u[i], a, s);
    h[i] = v;
    hb[i] = f2b(v);
}

__global__ void pool_kernel(const float* __restrict__ h, const int* __restrict__ batch,
                            float* __restrict__ pool, float* __restrict__ cnt, int n)
{
    const int c = threadIdx.x & (H - 1);
    const int half = threadIdx.x >> 7;
    const int r0 = blockIdx.x * 256 + half * 128;
    if (r0 >= n) return;
    const int rend = min(r0 + 128, n);
    int gprev = batch[r0];
    float acc = 0.f;
    int run = 0;
    for (int r = r0; r < rend; ++r) {
        const int g = batch[r];
        if (g != gprev) {
            atomicAdd(&pool[gprev * H + c], acc);
            if (c == 0) atomicAdd(&cnt[gprev], (float)run);
            acc = 0.f; run = 0; gprev = g;
        }
        acc += h[(size_t)r * H + c];
        run++;
    }
    atomicAdd(&pool[gprev * H + c], acc);
    if (c == 0) atomicAdd(&cnt[gprev], (float)run);
}

__global__ void readout_kernel(const float* __restrict__ pool, const float* __restrict__ cnt,
                               const float* __restrict__ Wr1, const float* __restrict__ br1,
                               const float* __restrict__ Wr2, const float* __restrict__ br2,
                               float* __restrict__ out)
{
    __shared__ float hg[H];
    __shared__ float r1[H];
    const int g = blockIdx.x;
    const int j = threadIdx.x;
    hg[j] = pool[g * H + j] / fmaxf(cnt[g], 1.0f);
    __syncthreads();
    float acc = br1[j];
    for (int k = 0; k < H; ++k) acc = fmaf(hg[k], Wr1[k * H + j], acc);
    r1[j] = fmaxf(acc, 0.f);
    __syncthreads();
    if (j < NCLS) {
        float o = br2[j];
        for (int k = 0; k < H; ++k) o = fmaf(r1[k], Wr2[k * NCLS + j], o);
        out[g * NCLS + j] = o;
    }
}

// ---------------------------------------------------------------------------
extern "C" void kernel_launch(void* const* d_in, const int* in_sizes, int n_in,
                              void* d_out, int out_size, void* d_ws, size_t ws_size,
                              hipStream_t stream)
{
    const float* x       = (const float*)d_in[0];
    const float* pe      = (const float*)d_in[1];
    const int*   ei      = (const int*)d_in[2];
    const float* ea      = (const float*)d_in[3];
    const int*   batch   = (const int*)d_in[4];
    const float* W_in    = (const float*)d_in[5];
    const float* b_in    = (const float*)d_in[6];
    const float* We_edge = (const float*)d_in[7];
    const float* be_edge = (const float*)d_in[8];
    const float* eps     = (const float*)d_in[9];
    const float* W1g     = (const float*)d_in[10];
    const float* b1g     = (const float*)d_in[11];
    const float* W2g     = (const float*)d_in[12];
    const float* b2g     = (const float*)d_in[13];
    const float* bn1g    = (const float*)d_in[14];
    const float* bn1b    = (const float*)d_in[15];
    const float* W1f     = (const float*)d_in[16];
    const float* b1f     = (const float*)d_in[17];
    const float* W2f     = (const float*)d_in[18];
    const float* b2f     = (const float*)d_in[19];
    const float* bn2g    = (const float*)d_in[20];
    const float* bn2b    = (const float*)d_in[21];
    const float* Wr1     = (const float*)d_in[22];
    const float* br1     = (const float*)d_in[23];
    const float* Wr2     = (const float*)d_in[24];
    const float* br2     = (const float*)d_in[25];
    float* out = (float*)d_out;

    const size_t NH = (size_t)NN * H;
    float* hbuf  = (float*)d_ws;                     // [NN,H] fp32
    float* zbuf  = hbuf + NH;                        // [NN,H] fp32
    float* tbuf  = zbuf + NH;                        // [NN,H] fp32
    unsigned short* z1 = (unsigned short*)(tbuf + NH);  // [NN,H2] bf16 (xin fp32 scratch too)
    float* stats = (float*)(z1 + (size_t)NN * H2);   // [4 layers][2 slabs][256]
    float* pool  = stats + 2048;                     // [NG,H]
    float* cnt   = pool + NG * H;                    // [NG]
    int*   rowptr = (int*)(cnt + NG);                // [NN+1]
    int*   cursor = rowptr + NN + 1;                 // [NN]
    int*   deg    = cursor + NN;                     // [NN]
    int*   src_s  = deg + NN;                        // [NE]
    float* ea_s   = (float*)(src_s + NE);            // [NE,16]
    unsigned short* hb = (unsigned short*)(ea_s + (size_t)NE * 16);  // [NN,H] bf16
    unsigned short* wt = hb + NH;                    // 16 matrices x 2*K*N
    unsigned short* wt1g = wt;
    unsigned short* wt2g = wt + 4 * 65536;
    unsigned short* wt1f = wt + 8 * 65536;
    unsigned short* wt2f = wt + 12 * 65536;

    const dim3 blk(256);
    const dim3 mg1((NN + 127) / 128, 1);
    const dim3 mg2((NN + 127) / 128, 2);
    const int ew_grid = (int)(NH / 256);
    const float inv_n = 1.0f / (float)NN;

    // ---- weight prep ----
    wprep_kernel<<<512, blk, 0, stream>>>(W1g, wt1g, 128, 256);
    wprep_kernel<<<512, blk, 0, stream>>>(W2g, wt2g, 256, 128);
    wprep_kernel<<<512, blk, 0, stream>>>(W1f, wt1f, 128, 256);
    wprep_kernel<<<512, blk, 0, stream>>>(W2f, wt2f, 256, 128);

    // ---- CSR build ----
    hipMemsetAsync(deg, 0, NN * sizeof(int), stream);
    hipMemsetAsync(stats, 0, 2048 * sizeof(float), stream);
    hist_kernel<<<(NE + 255) / 256, blk, 0, stream>>>(ei, deg);
    scan_kernel<<<1, 1024, 0, stream>>>(deg, rowptr, cursor);
    scatter_kernel<<<(NE + 255) / 256, blk, 0, stream>>>(ei, ea, cursor, src_s, ea_s);

    // ---- input projection ----
    concat_kernel<<<(NN * FIN) / 256, blk, 0, stream>>>(x, pe, (float*)z1);
    gemm_kernel<<<mg1, blk, 0, stream>>>((float*)z1, W_in, b_in, hbuf, hb, NN, FIN, H, 1);

    for (int l = 0; l < 4; ++l) {
        float* s1 = stats + (size_t)l * 512;
        float* s2 = s1 + 256;

        // z = (1+eps)*h + sum relu(h[src] + elin)
        agg_kernel<<<(NN + 3) / 4, blk, 0, stream>>>(hbuf, hb, rowptr, src_s, ea_s,
                                                     We_edge + (size_t)l * 16 * H,
                                                     be_edge + (size_t)l * H, eps, l, zbuf);

        // GIN MLP: z1 = relu(z@W1g+b1g); t = z1@W2g+b2g (+stats s1)
        mgemm<false, true, false><<<mg2, blk, 0, stream>>>(
            zbuf, wt1g + (size_t)l * 65536, b1g + (size_t)l * H2, nullptr, z1,
            NN, 128, 256, 1, nullptr, nullptr, nullptr, nullptr, nullptr, nullptr, inv_n);
        mgemm<true, false, false><<<mg1, blk, 0, stream>>>(
            z1, wt2g + (size_t)l * 65536, b2g + (size_t)l * H, nullptr, tbuf,
            NN, 256, 128, 0, s1, nullptr, nullptr, nullptr, nullptr, nullptr, inv_n);

        // fused: z = relu(bn1(t)) + h  -> zbuf; z1 = relu(z@W1f+b1f)
        mgemm<false, true, true><<<mg2, blk, 0, stream>>>(
            tbuf, wt1f + (size_t)l * 65536, b1f + (size_t)l * H2, nullptr, z1,
            NN, 128, 256, 1, nullptr, s1, bn1g + (size_t)l * H, bn1b + (size_t)l * H,
            hbuf, zbuf, inv_n);

        // u = z1@W2f + b2f + z (+stats s2)
        mgemm<true, false, false><<<mg1, blk, 0, stream>>>(
            z1, wt2f + (size_t)l * 65536, b2f + (size_t)l * H, zbuf, tbuf,
            NN, 256, 128, 0, s2, nullptr, nullptr, nullptr, nullptr, nullptr, inv_n);

        // h = bn2(u)
        bn_apply_kernel<<<ew_grid, blk, 0, stream>>>(tbuf, s2, bn2g + (size_t)l * H,
                                                     bn2b + (size_t)l * H, hbuf, hb, inv_n);
    }

    hipMemsetAsync(pool, 0, (NG * H + NG) * sizeof(float), stream);
    pool_kernel<<<(NN + 255) / 256, blk, 0, stream>>>(hbuf, batch, pool, cnt, NN);
    readout_kernel<<<NG, H, 0, stream>>>(pool, cnt, Wr1, br1, Wr2, br2, out);
}

// Round 5
// 1329.183 us; speedup vs baseline: 2.4665x; 1.0737x over previous
//
#include <hip/hip_runtime.h>
#include <hip/hip_bf16.h>

#define NN 50000
#define NE 800000
#define FIN 80
#define H 128
#define H2 256
#define NG 64
#define NCLS 10
#define BN_EPS 1e-5f
#define NB 196   // ceil(NN/256)

typedef __attribute__((ext_vector_type(8))) short bf16x8;
typedef __attribute__((ext_vector_type(8))) unsigned short us8;
typedef __attribute__((ext_vector_type(4))) float f32x4;

__device__ __forceinline__ unsigned short f2b(float f) {
    __hip_bfloat16 h = __float2bfloat16(f);   // RNE
    return *(unsigned short*)&h;
}
__device__ __forceinline__ float b2f(unsigned short u) {
    unsigned v = (unsigned)u << 16;
    return __uint_as_float(v);
}

// ---------------------------------------------------------------------------
// Weight prep: W[L][K][Nn] fp32 -> per-layer {hi,lo} bf16 planes, k-blocked:
// dst[l][ ((p*KB + kb)*Nn + n)*32 + kk ]
// ---------------------------------------------------------------------------
__global__ void wprep_kernel(const float* __restrict__ W, unsigned short* __restrict__ Wt,
                             int K, int Nn)
{
    const int idx = blockIdx.x * 256 + threadIdx.x;
    const int per = K * Nn;
    const int l = idx / per;
    const int r = idx - l * per;
    const int k = r / Nn;
    const int n = r - k * Nn;
    const float wv = W[idx];
    const unsigned short hi = f2b(wv);
    const unsigned short lo = f2b(wv - b2f(hi));
    const int KB = K >> 5;
    const int kb = k >> 5, kk = k & 31;
    unsigned short* base = Wt + (size_t)l * 2 * per;
    base[((size_t)(0 * KB + kb) * Nn + n) * 32 + kk] = hi;
    base[((size_t)(1 * KB + kb) * Nn + n) * 32 + kk] = lo;
}

// ---------------------------------------------------------------------------
// MFMA GEMM (same structure as R4): see template flags.
// ---------------------------------------------------------------------------
template<bool ABF, bool CBF, bool ZF>
__global__ __launch_bounds__(256, 2)
void mgemm(const void* __restrict__ Ap, const unsigned short* __restrict__ Wt,
           const float* __restrict__ bias, const float* __restrict__ resid,
           void* __restrict__ Cp, int M, int K, int Nn, int relu,
           float* __restrict__ statsOut,
           const float* __restrict__ statsIn, const float* __restrict__ bng,
           const float* __restrict__ bnb, const float* __restrict__ hres,
           float* __restrict__ zout, float inv_n)
{
    __shared__ unsigned short sA[128][32];      // A[m][k]   8 KB
    __shared__ unsigned short sB[2][128][32];   // Bt[p][n][k] 16 KB
    __shared__ float sAB[128];
    __shared__ float sSH[128];

    const int tid = threadIdx.x;
    const int m0 = blockIdx.x * 128;
    const int n0 = blockIdx.y * 128;
    const int lane = tid & 63;
    const int w = tid >> 6;
    const int KB = K >> 5;

    if (ZF) {
        if (tid < 128) {
            const float mean = statsIn[tid] * inv_n;
            const float var = statsIn[128 + tid] * inv_n - mean * mean;
            const float a = bng[tid] * rsqrtf(var + BN_EPS);
            sAB[tid] = a;
            sSH[tid] = fmaf(-mean, a, bnb[tid]);
        }
    }

    f32x4 acc[2][8];
#pragma unroll
    for (int r = 0; r < 2; ++r)
#pragma unroll
        for (int c = 0; c < 8; ++c) acc[r][c] = (f32x4)(0.f);

    const int arow = tid >> 1;
    const int akh = (tid & 1) * 16;
    const int gm = m0 + arow;
    const int fr = lane & 15;
    const int fq = (lane >> 4) * 8;

    for (int kb = 0; kb < KB; ++kb) {
        const int k0 = kb * 32;
        __syncthreads();
        // ---- stage A ----
        if (ABF) {
            if (gm < M) {
                const unsigned short* Ab = (const unsigned short*)Ap + (size_t)gm * K + k0 + akh;
                *(float4*)&sA[arow][akh]     = *(const float4*)Ab;
                *(float4*)&sA[arow][akh + 8] = *(const float4*)(Ab + 8);
            } else {
                *(float4*)&sA[arow][akh]     = make_float4(0.f, 0.f, 0.f, 0.f);
                *(float4*)&sA[arow][akh + 8] = make_float4(0.f, 0.f, 0.f, 0.f);
            }
        } else if (ZF) {
            if (gm < M) {
                const float* tf = (const float*)Ap + (size_t)gm * K + k0 + akh;
                const float* hf = hres + (size_t)gm * K + k0 + akh;
                float zv[16];
#pragma unroll
                for (int i = 0; i < 16; ++i) {
                    const int c = k0 + akh + i;
                    zv[i] = fmaxf(fmaf(tf[i], sAB[c], sSH[c]), 0.f) + hf[i];
                }
                if (blockIdx.y == 0) {
                    float* zo = zout + (size_t)gm * K + k0 + akh;
#pragma unroll
                    for (int i = 0; i < 16; i += 4)
                        *(float4*)(zo + i) = make_float4(zv[i], zv[i + 1], zv[i + 2], zv[i + 3]);
                }
                us8 p0, p1;
#pragma unroll
                for (int i = 0; i < 8; ++i) { p0[i] = f2b(zv[i]); p1[i] = f2b(zv[8 + i]); }
                *(us8*)&sA[arow][akh]     = p0;
                *(us8*)&sA[arow][akh + 8] = p1;
            } else {
                *(float4*)&sA[arow][akh]     = make_float4(0.f, 0.f, 0.f, 0.f);
                *(float4*)&sA[arow][akh + 8] = make_float4(0.f, 0.f, 0.f, 0.f);
            }
        } else {
            if (gm < M) {
                const float* Af = (const float*)Ap + (size_t)gm * K + k0 + akh;
                const float4 v0 = *(const float4*)(Af);
                const float4 v1 = *(const float4*)(Af + 4);
                const float4 v2 = *(const float4*)(Af + 8);
                const float4 v3 = *(const float4*)(Af + 12);
                const float vals[16] = {v0.x, v0.y, v0.z, v0.w, v1.x, v1.y, v1.z, v1.w,
                                        v2.x, v2.y, v2.z, v2.w, v3.x, v3.y, v3.z, v3.w};
                us8 p0, p1;
#pragma unroll
                for (int i = 0; i < 8; ++i) { p0[i] = f2b(vals[i]); p1[i] = f2b(vals[8 + i]); }
                *(us8*)&sA[arow][akh]     = p0;
                *(us8*)&sA[arow][akh + 8] = p1;
            } else {
                *(float4*)&sA[arow][akh]     = make_float4(0.f, 0.f, 0.f, 0.f);
                *(float4*)&sA[arow][akh + 8] = make_float4(0.f, 0.f, 0.f, 0.f);
            }
        }
        // ---- stage B ----
#pragma unroll
        for (int p = 0; p < 2; ++p) {
            const unsigned short* src = Wt + ((size_t)(p * KB + kb) * Nn + n0) * 32 + tid * 16;
            unsigned short* dst = &sB[p][0][0] + tid * 16;
            *(float4*)dst       = *(const float4*)src;
            *(float4*)(dst + 8) = *(const float4*)(src + 8);
        }
        __syncthreads();
        // ---- MFMA ----
        const bf16x8 a0 = *(const bf16x8*)&sA[w * 32 + fr][fq];
        const bf16x8 a1 = *(const bf16x8*)&sA[w * 32 + 16 + fr][fq];
#pragma unroll
        for (int c = 0; c < 8; ++c) {
            const bf16x8 bh = *(const bf16x8*)&sB[0][c * 16 + fr][fq];
            const bf16x8 bl = *(const bf16x8*)&sB[1][c * 16 + fr][fq];
            acc[0][c] = __builtin_amdgcn_mfma_f32_16x16x32_bf16(a0, bh, acc[0][c], 0, 0, 0);
            acc[0][c] = __builtin_amdgcn_mfma_f32_16x16x32_bf16(a0, bl, acc[0][c], 0, 0, 0);
            acc[1][c] = __builtin_amdgcn_mfma_f32_16x16x32_bf16(a1, bh, acc[1][c], 0, 0, 0);
            acc[1][c] = __builtin_amdgcn_mfma_f32_16x16x32_bf16(a1, bl, acc[1][c], 0, 0, 0);
        }
    }

    // ---- epilogue ----
    float s[8], q[8];
#pragma unroll
    for (int c = 0; c < 8; ++c) { s[c] = 0.f; q[c] = 0.f; }
    const int crow4 = (lane >> 4) * 4;
#pragma unroll
    for (int r = 0; r < 2; ++r) {
        const int rbase = m0 + w * 32 + r * 16 + crow4;
#pragma unroll
        for (int c = 0; c < 8; ++c) {
            const int gc = n0 + c * 16 + fr;
            const float bb = bias[gc];
#pragma unroll
            for (int reg = 0; reg < 4; ++reg) {
                const int gr = rbase + reg;
                if (gr >= M) continue;
                float o = acc[r][c][reg] + bb;
                if (resid) o += resid[(size_t)gr * Nn + gc];
                if (relu) o = fmaxf(o, 0.f);
                if (statsOut) { s[c] += o; q[c] = fmaf(o, o, q[c]); }
                if (CBF) ((unsigned short*)Cp)[(size_t)gr * Nn + gc] = f2b(o);
                else     ((float*)Cp)[(size_t)gr * Nn + gc] = o;
            }
        }
    }

    if (statsOut) {
#pragma unroll
        for (int c = 0; c < 8; ++c) {
            s[c] += __shfl_xor(s[c], 32, 64); s[c] += __shfl_xor(s[c], 16, 64);
            q[c] += __shfl_xor(q[c], 32, 64); q[c] += __shfl_xor(q[c], 16, 64);
        }
        __syncthreads();
        float* red = (float*)sA;
        if (lane < 16) {
#pragma unroll
            for (int c = 0; c < 8; ++c) {
                red[w * 128 + c * 16 + lane]       = s[c];
                red[512 + w * 128 + c * 16 + lane] = q[c];
            }
        }
        __syncthreads();
        if (tid < 128) {
            const float ss = red[tid] + red[128 + tid] + red[256 + tid] + red[384 + tid];
            const float qq = red[512 + tid] + red[640 + tid] + red[768 + tid] + red[896 + tid];
            atomicAdd(&statsOut[tid], ss);
            atomicAdd(&statsOut[128 + tid], qq);
        }
    }
}

// ---------------------------------------------------------------------------
// fp32 input-projection GEMM, reads x||pe directly (no concat pass).
// K=FIN=80: cols 0-63 from x, 64-79 from pe (8-aligned chunks never straddle).
// ---------------------------------------------------------------------------
__global__ __launch_bounds__(256, 4)
void inproj_kernel(const float* __restrict__ x, const float* __restrict__ pe,
                   const float* __restrict__ W, const float* __restrict__ bias,
                   float* __restrict__ C, unsigned short* __restrict__ Cb, int M)
{
    __shared__ float aT[16][128];
    __shared__ float wsh[16][128];

    const int tid = threadIdx.x;
    const int m0 = blockIdx.x * 128;
    const int rm = (tid >> 4) * 8;
    const int rn = (tid & 15) * 8;

    float acc[8][8];
#pragma unroll
    for (int i = 0; i < 8; ++i)
#pragma unroll
        for (int j = 0; j < 8; ++j) acc[i][j] = 0.f;

    const int lm = tid & 127;
    const int kq = (tid >> 7) * 8;
    const int wk = tid >> 4;
    const int wj = (tid & 15) * 8;

    for (int k0 = 0; k0 < FIN; k0 += 16) {
        {
            const int gm = m0 + lm;
            const int c = k0 + kq;           // 8-aligned, in [0,72]
            if (gm < M) {
                const float* srcp = (c < 64) ? (x + (size_t)gm * 64 + c)
                                             : (pe + (size_t)gm * 16 + (c - 64));
                const float4 v0 = *(const float4*)srcp;
                const float4 v1 = *(const float4*)(srcp + 4);
                aT[kq + 0][lm] = v0.x; aT[kq + 1][lm] = v0.y;
                aT[kq + 2][lm] = v0.z; aT[kq + 3][lm] = v0.w;
                aT[kq + 4][lm] = v1.x; aT[kq + 5][lm] = v1.y;
                aT[kq + 6][lm] = v1.z; aT[kq + 7][lm] = v1.w;
            } else {
#pragma unroll
                for (int i = 0; i < 8; ++i) aT[kq + i][lm] = 0.f;
            }
        }
        {
            const float4 w0 = *(const float4*)&W[(size_t)(k0 + wk) * H + wj];
            const float4 w1 = *(const float4*)&W[(size_t)(k0 + wk) * H + wj + 4];
            *(float4*)&wsh[wk][wj]     = w0;
            *(float4*)&wsh[wk][wj + 4] = w1;
        }
        __syncthreads();
#pragma unroll
        for (int k = 0; k < 16; ++k) {
            const float4 a0 = *(const float4*)&aT[k][rm];
            const float4 a1 = *(const float4*)&aT[k][rm + 4];
            const float4 b0 = *(const float4*)&wsh[k][rn];
            const float4 b1 = *(const float4*)&wsh[k][rn + 4];
            const float av[8] = {a0.x, a0.y, a0.z, a0.w, a1.x, a1.y, a1.z, a1.w};
            const float bv[8] = {b0.x, b0.y, b0.z, b0.w, b1.x, b1.y, b1.z, b1.w};
#pragma unroll
            for (int i = 0; i < 8; ++i)
#pragma unroll
                for (int j = 0; j < 8; ++j)
                    acc[i][j] = fmaf(av[i], bv[j], acc[i][j]);
        }
        __syncthreads();
    }

    float bv[8];
#pragma unroll
    for (int j = 0; j < 8; ++j) bv[j] = bias[rn + j];
#pragma unroll
    for (int i = 0; i < 8; ++i) {
        const int gm = m0 + rm + i;
        if (gm >= M) continue;
        float o[8];
#pragma unroll
        for (int j = 0; j < 8; ++j) o[j] = fmaxf(acc[i][j] + bv[j], 0.f);
        *(float4*)&C[(size_t)gm * H + rn]     = make_float4(o[0], o[1], o[2], o[3]);
        *(float4*)&C[(size_t)gm * H + rn + 4] = make_float4(o[4], o[5], o[6], o[7]);
        us8 pk;
#pragma unroll
        for (int j = 0; j < 8; ++j) pk[j] = f2b(o[j]);
        *(us8*)&Cb[(size_t)gm * H + rn] = pk;
    }
}

// ---------------------------------------------------------------------------
// CSR build: histogram -> 3-stage parallel scan -> scatter
// ---------------------------------------------------------------------------
__global__ void hist_kernel(const int* __restrict__ ei, int* __restrict__ deg)
{
    const int e = blockIdx.x * 256 + threadIdx.x;
    if (e < NE) atomicAdd(&deg[ei[NE + e]], 1);
}

__global__ void bsum_kernel(const int* __restrict__ deg, int* __restrict__ bsum)
{
    const int tid = threadIdx.x;
    const int i = blockIdx.x * 256 + tid;
    int v = (i < NN) ? deg[i] : 0;
#pragma unroll
    for (int off = 32; off > 0; off >>= 1) v += __shfl_down(v, off, 64);
    __shared__ int ws[4];
    if ((tid & 63) == 0) ws[tid >> 6] = v;
    __syncthreads();
    if (tid == 0) bsum[blockIdx.x] = ws[0] + ws[1] + ws[2] + ws[3];
}

__global__ void bscan_kernel(int* __restrict__ bsum)   // exclusive scan, NB elems
{
    __shared__ int sh[256];
    const int tid = threadIdx.x;
    sh[tid] = (tid < NB) ? bsum[tid] : 0;
    __syncthreads();
    for (int off = 1; off < 256; off <<= 1) {
        const int t = (tid >= off) ? sh[tid - off] : 0;
        __syncthreads();
        sh[tid] += t;
        __syncthreads();
    }
    if (tid < NB) bsum[tid] = (tid == 0) ? 0 : sh[tid - 1];
}

__global__ void bwrite_kernel(const int* __restrict__ deg, const int* __restrict__ boff,
                              int* __restrict__ rowptr, int* __restrict__ cursor)
{
    __shared__ int sh[256];
    const int tid = threadIdx.x;
    const int i = blockIdx.x * 256 + tid;
    const int v = (i < NN) ? deg[i] : 0;
    sh[tid] = v;
    __syncthreads();
    for (int off = 1; off < 256; off <<= 1) {
        const int t = (tid >= off) ? sh[tid - off] : 0;
        __syncthreads();
        sh[tid] += t;
        __syncthreads();
    }
    if (i < NN) {
        const int pos = boff[blockIdx.x] + sh[tid] - v;   // exclusive
        rowptr[i] = pos;
        cursor[i] = pos;
    }
    if (blockIdx.x == 0 && tid == 0) rowptr[NN] = NE;
}

__global__ void scatter_kernel(const int* __restrict__ ei, const float* __restrict__ ea,
                               int* __restrict__ cursor, int* __restrict__ src_s,
                               float* __restrict__ ea_s)
{
    const int e = blockIdx.x * 256 + threadIdx.x;
    if (e >= NE) return;
    const int d = ei[NE + e];
    const int pos = atomicAdd(&cursor[d], 1);
    src_s[pos] = ei[e];
    const float4* sp = (const float4*)&ea[(size_t)e * 16];
    float4* dp = (float4*)&ea_s[(size_t)pos * 16];
    dp[0] = sp[0]; dp[1] = sp[1]; dp[2] = sp[2]; dp[3] = sp[3];
}

// ---------------------------------------------------------------------------
// Aggregation: z = (1+eps)*h + sum relu(h[src] + ea@We + be). One wave/node.
// ---------------------------------------------------------------------------
__global__ __launch_bounds__(256)
void agg_kernel(const float* __restrict__ h, const unsigned short* __restrict__ hb,
                const int* __restrict__ rowptr, const int* __restrict__ src_s,
                const float* __restrict__ ea_s, const float* __restrict__ We,
                const float* __restrict__ be, const float* __restrict__ eps, int l,
                float* __restrict__ z)
{
    const int lane = threadIdx.x & 63;
    const int w = threadIdx.x >> 6;
    const int n = blockIdx.x * 4 + w;
    if (n >= NN) return;

    float w0[16], w1[16];
#pragma unroll
    for (int k = 0; k < 16; ++k) {
        const float2 wv = *(const float2*)&We[k * H + 2 * lane];
        w0[k] = wv.x; w1[k] = wv.y;
    }
    const float2 bev = *(const float2*)&be[2 * lane];

    const int beg = __builtin_amdgcn_readfirstlane(rowptr[n]);
    const int end = __builtin_amdgcn_readfirstlane(rowptr[n + 1]);

    const float e1 = 1.0f + eps[l];
    const float2 hv0 = *(const float2*)&h[(size_t)n * H + 2 * lane];
    float acc0 = e1 * hv0.x;
    float acc1 = e1 * hv0.y;

    for (int i0 = beg; i0 < end; i0 += 8) {
        const int jn = min(8, end - i0);
        int srcs[8];
#pragma unroll
        for (int j = 0; j < 8; ++j)
            srcs[j] = src_s[(i0 + j < end) ? (i0 + j) : (end - 1)];
        unsigned hraw[8];
#pragma unroll
        for (int j = 0; j < 8; ++j)
            hraw[j] = *(const unsigned*)&hb[(size_t)srcs[j] * H + 2 * lane];
#pragma unroll
        for (int j = 0; j < 8; ++j) {
            if (j >= jn) break;
            const float* ar = ea_s + (size_t)(i0 + j) * 16;
            float s0 = bev.x, s1 = bev.y;
#pragma unroll
            for (int k = 0; k < 16; ++k) {
                const float a = ar[k];
                s0 = fmaf(a, w0[k], s0);
                s1 = fmaf(a, w1[k], s1);
            }
            const float hx = __uint_as_float(hraw[j] << 16);
            const float hy = __uint_as_float(hraw[j] & 0xffff0000u);
            acc0 += fmaxf(hx + s0, 0.f);
            acc1 += fmaxf(hy + s1, 0.f);
        }
    }
    *(float2*)&z[(size_t)n * H + 2 * lane] = make_float2(acc0, acc1);
}

// ---------------------------------------------------------------------------
// bn_apply / pool / readout
// ---------------------------------------------------------------------------
__global__ void bn_apply_kernel(const float* __restrict__ u, const float* __restrict__ st,
                                const float* __restrict__ g, const float* __restrict__ b,
                                float* __restrict__ h, unsigned short* __restrict__ hb,
                                float inv_n)
{
    const int i = blockIdx.x * 256 + threadIdx.x;
    const int c = i & (H - 1);
    const float mean = st[c] * inv_n;
    const float var = st[H + c] * inv_n - mean * mean;
    const float a = g[c] * rsqrtf(var + BN_EPS);
    const float s = fmaf(-mean, a, b[c]);
    const float v = fmaf(u[i], a, s);
    h[i] = v;
    hb[i] = f2b(v);
}

__global__ void pool_kernel(const float* __restrict__ h, const int* __restrict__ batch,
                            float* __restrict__ pool, float* __restrict__ cnt, int n)
{
    const int c = threadIdx.x & (H - 1);
    const int half = threadIdx.x >> 7;
    const int r0 = blockIdx.x * 256 + half * 128;
    if (r0 >= n) return;
    const int rend = min(r0 + 128, n);
    int gprev = batch[r0];
    float acc = 0.f;
    int run = 0;
    for (int r = r0; r < rend; ++r) {
        const int g = batch[r];
        if (g != gprev) {
            atomicAdd(&pool[gprev * H + c], acc);
            if (c == 0) atomicAdd(&cnt[gprev], (float)run);
            acc = 0.f; run = 0; gprev = g;
        }
        acc += h[(size_t)r * H + c];
        run++;
    }
    atomicAdd(&pool[gprev * H + c], acc);
    if (c == 0) atomicAdd(&cnt[gprev], (float)run);
}

__global__ void readout_kernel(const float* __restrict__ pool, const float* __restrict__ cnt,
                               const float* __restrict__ Wr1, const float* __restrict__ br1,
                               const float* __restrict__ Wr2, const float* __restrict__ br2,
                               float* __restrict__ out)
{
    __shared__ float hg[H];
    __shared__ float r1[H];
    const int g = blockIdx.x;
    const int j = threadIdx.x;
    hg[j] = pool[g * H + j] / fmaxf(cnt[g], 1.0f);
    __syncthreads();
    float acc = br1[j];
    for (int k = 0; k < H; ++k) acc = fmaf(hg[k], Wr1[k * H + j], acc);
    r1[j] = fmaxf(acc, 0.f);
    __syncthreads();
    if (j < NCLS) {
        float o = br2[j];
        for (int k = 0; k < H; ++k) o = fmaf(r1[k], Wr2[k * NCLS + j], o);
        out[g * NCLS + j] = o;
    }
}

// ---------------------------------------------------------------------------
extern "C" void kernel_launch(void* const* d_in, const int* in_sizes, int n_in,
                              void* d_out, int out_size, void* d_ws, size_t ws_size,
                              hipStream_t stream)
{
    const float* x       = (const float*)d_in[0];
    const float* pe      = (const float*)d_in[1];
    const int*   ei      = (const int*)d_in[2];
    const float* ea      = (const float*)d_in[3];
    const int*   batch   = (const int*)d_in[4];
    const float* W_in    = (const float*)d_in[5];
    const float* b_in    = (const float*)d_in[6];
    const float* We_edge = (const float*)d_in[7];
    const float* be_edge = (const float*)d_in[8];
    const float* eps     = (const float*)d_in[9];
    const float* W1g     = (const float*)d_in[10];
    const float* b1g     = (const float*)d_in[11];
    const float* W2g     = (const float*)d_in[12];
    const float* b2g     = (const float*)d_in[13];
    const float* bn1g    = (const float*)d_in[14];
    const float* bn1b    = (const float*)d_in[15];
    const float* W1f     = (const float*)d_in[16];
    const float* b1f     = (const float*)d_in[17];
    const float* W2f     = (const float*)d_in[18];
    const float* b2f     = (const float*)d_in[19];
    const float* bn2g    = (const float*)d_in[20];
    const float* bn2b    = (const float*)d_in[21];
    const float* Wr1     = (const float*)d_in[22];
    const float* br1     = (const float*)d_in[23];
    const float* Wr2     = (const float*)d_in[24];
    const float* br2     = (const float*)d_in[25];
    float* out = (float*)d_out;

    const size_t NH = (size_t)NN * H;
    float* hbuf  = (float*)d_ws;                     // [NN,H] fp32
    float* zbuf  = hbuf + NH;                        // [NN,H] fp32
    float* tbuf  = zbuf + NH;                        // [NN,H] fp32
    unsigned short* z1 = (unsigned short*)(tbuf + NH);  // [NN,H2] bf16
    float* stats = (float*)(z1 + (size_t)NN * H2);   // [4 layers][2 slabs][256]
    float* pool  = stats + 2048;                     // [NG,H]
    float* cnt   = pool + NG * H;                    // [NG]
    int*   rowptr = (int*)(cnt + NG);                // [NN+1]
    int*   cursor = rowptr + NN + 1;                 // [NN]
    int*   deg    = cursor + NN;                     // [NN]
    int*   bsum   = deg + NN;                        // [NB]
    int*   src_s  = bsum + 256;                      // [NE]
    float* ea_s   = (float*)(src_s + NE);            // [NE,16]
    unsigned short* hb = (unsigned short*)(ea_s + (size_t)NE * 16);  // [NN,H] bf16
    unsigned short* wt = hb + NH;                    // 16 matrices x 2*K*N
    unsigned short* wt1g = wt;
    unsigned short* wt2g = wt + 4 * 65536;
    unsigned short* wt1f = wt + 8 * 65536;
    unsigned short* wt2f = wt + 12 * 65536;

    const dim3 blk(256);
    const dim3 mg1((NN + 127) / 128, 1);
    const dim3 mg2((NN + 127) / 128, 2);
    const int ew_grid = (int)(NH / 256);
    const float inv_n = 1.0f / (float)NN;

    // ---- weight prep ----
    wprep_kernel<<<512, blk, 0, stream>>>(W1g, wt1g, 128, 256);
    wprep_kernel<<<512, blk, 0, stream>>>(W2g, wt2g, 256, 128);
    wprep_kernel<<<512, blk, 0, stream>>>(W1f, wt1f, 128, 256);
    wprep_kernel<<<512, blk, 0, stream>>>(W2f, wt2f, 256, 128);

    // ---- CSR build (parallel scan) ----
    hipMemsetAsync(deg, 0, NN * sizeof(int), stream);
    hipMemsetAsync(stats, 0, 2048 * sizeof(float), stream);
    hist_kernel<<<(NE + 255) / 256, blk, 0, stream>>>(ei, deg);
    bsum_kernel<<<NB, blk, 0, stream>>>(deg, bsum);
    bscan_kernel<<<1, blk, 0, stream>>>(bsum);
    bwrite_kernel<<<NB, blk, 0, stream>>>(deg, bsum, rowptr, cursor);
    scatter_kernel<<<(NE + 255) / 256, blk, 0, stream>>>(ei, ea, cursor, src_s, ea_s);

    // ---- input projection (reads x||pe directly) ----
    inproj_kernel<<<mg1, blk, 0, stream>>>(x, pe, W_in, b_in, hbuf, hb, NN);

    for (int l = 0; l < 4; ++l) {
        float* s1 = stats + (size_t)l * 512;
        float* s2 = s1 + 256;

        agg_kernel<<<(NN + 3) / 4, blk, 0, stream>>>(hbuf, hb, rowptr, src_s, ea_s,
                                                     We_edge + (size_t)l * 16 * H,
                                                     be_edge + (size_t)l * H, eps, l, zbuf);

        mgemm<false, true, false><<<mg2, blk, 0, stream>>>(
            zbuf, wt1g + (size_t)l * 65536, b1g + (size_t)l * H2, nullptr, z1,
            NN, 128, 256, 1, nullptr, nullptr, nullptr, nullptr, nullptr, nullptr, inv_n);
        mgemm<true, false, false><<<mg1, blk, 0, stream>>>(
            z1, wt2g + (size_t)l * 65536, b2g + (size_t)l * H, nullptr, tbuf,
            NN, 256, 128, 0, s1, nullptr, nullptr, nullptr, nullptr, nullptr, inv_n);

        mgemm<false, true, true><<<mg2, blk, 0, stream>>>(
            tbuf, wt1f + (size_t)l * 65536, b1f + (size_t)l * H2, nullptr, z1,
            NN, 128, 256, 1, nullptr, s1, bn1g + (size_t)l * H, bn1b + (size_t)l * H,
            hbuf, zbuf, inv_n);

        mgemm<true, false, false><<<mg1, blk, 0, stream>>>(
            z1, wt2f + (size_t)l * 65536, b2f + (size_t)l * H, zbuf, tbuf,
            NN, 256, 128, 0, s2, nullptr, nullptr, nullptr, nullptr, nullptr, inv_n);

        bn_apply_kernel<<<ew_grid, blk, 0, stream>>>(tbuf, s2, bn2g + (size_t)l * H,
                                                     bn2b + (size_t)l * H, hbuf, hb, inv_n);
    }

    hipMemsetAsync(pool, 0, (NG * H + NG) * sizeof(float), stream);
    pool_kernel<<<(NN + 255) / 256, blk, 0, stream>>>(hbuf, batch, pool, cnt, NN);
    readout_kernel<<<NG, H, 0, stream>>>(pool, cnt, Wr1, br1, Wr2, br2, out);
}

// Round 6
// 1319.090 us; speedup vs baseline: 2.4854x; 1.0077x over previous
//
#include <hip/hip_runtime.h>
#include <hip/hip_bf16.h>

#define NN 50000
#define NE 800000
#define FIN 80
#define H 128
#define H2 256
#define NG 64
#define NCLS 10
#define BN_EPS 1e-5f
#define NB 196    // ceil(NN/256)
#define LDK 40    // padded LDS leading dim (shorts): 80 B = 20 banks -> 2-way max

typedef __attribute__((ext_vector_type(8))) short bf16x8;
typedef __attribute__((ext_vector_type(8))) unsigned short us8;
typedef __attribute__((ext_vector_type(4))) float f32x4;

__device__ __forceinline__ unsigned short f2b(float f) {
    __hip_bfloat16 h = __float2bfloat16(f);   // RNE
    return *(unsigned short*)&h;
}
__device__ __forceinline__ float b2f(unsigned short u) {
    unsigned v = (unsigned)u << 16;
    return __uint_as_float(v);
}

// ---------------------------------------------------------------------------
// Weight prep (single dispatch, all 4 matrix groups):
// W[L][K][Nn] fp32 -> {hi,lo} bf16 planes, k-blocked:
// dst[l][ ((p*KB + kb)*Nn + n)*32 + kk ]
// ---------------------------------------------------------------------------
__global__ void wprep_all(const float* __restrict__ W1g, const float* __restrict__ W2g,
                          const float* __restrict__ W1f, const float* __restrict__ W2f,
                          unsigned short* __restrict__ wt)
{
    const int idx = blockIdx.x * 256 + threadIdx.x;   // grid = 2048*256 = 524288 exactly
    const int m = idx >> 17;                          // 131072 elems per matrix group
    const int r = idx & 131071;
    const float* W;
    unsigned short* Wt;
    int K, Nn;
    if (m == 0)      { W = W1g; Wt = wt;              K = 128; Nn = 256; }
    else if (m == 1) { W = W2g; Wt = wt + 4 * 65536;  K = 256; Nn = 128; }
    else if (m == 2) { W = W1f; Wt = wt + 8 * 65536;  K = 128; Nn = 256; }
    else             { W = W2f; Wt = wt + 12 * 65536; K = 256; Nn = 128; }
    const int per = K * Nn;        // 32768
    const int l = r / per;
    const int rr = r - l * per;
    const int k = rr / Nn;
    const int n = rr - k * Nn;
    const float wv = W[r];
    const unsigned short hi = f2b(wv);
    const unsigned short lo = f2b(wv - b2f(hi));
    const int KB = K >> 5;
    const int kb = k >> 5, kk = k & 31;
    unsigned short* base = Wt + (size_t)l * 2 * per;
    base[((size_t)(0 * KB + kb) * Nn + n) * 32 + kk] = hi;
    base[((size_t)(1 * KB + kb) * Nn + n) * 32 + kk] = lo;
}

// ---------------------------------------------------------------------------
// MFMA GEMM (structure as R5, LDS padded to LDK to kill bank conflicts).
// ---------------------------------------------------------------------------
template<bool ABF, bool CBF, bool ZF>
__global__ __launch_bounds__(256, 2)
void mgemm(const void* __restrict__ Ap, const unsigned short* __restrict__ Wt,
           const float* __restrict__ bias, const float* __restrict__ resid,
           void* __restrict__ Cp, int M, int K, int Nn, int relu,
           float* __restrict__ statsOut,
           const float* __restrict__ statsIn, const float* __restrict__ bng,
           const float* __restrict__ bnb, const float* __restrict__ hres,
           float* __restrict__ zout, float inv_n)
{
    __shared__ unsigned short sA[128][LDK];      // A[m][k]
    __shared__ unsigned short sB[2][128][LDK];   // Bt[p][n][k]
    __shared__ float sAB[128];
    __shared__ float sSH[128];

    const int tid = threadIdx.x;
    const int m0 = blockIdx.x * 128;
    const int n0 = blockIdx.y * 128;
    const int lane = tid & 63;
    const int w = tid >> 6;
    const int KB = K >> 5;

    if (ZF) {
        if (tid < 128) {
            const float mean = statsIn[tid] * inv_n;
            const float var = statsIn[128 + tid] * inv_n - mean * mean;
            const float a = bng[tid] * rsqrtf(var + BN_EPS);
            sAB[tid] = a;
            sSH[tid] = fmaf(-mean, a, bnb[tid]);
        }
    }

    f32x4 acc[2][8];
#pragma unroll
    for (int r = 0; r < 2; ++r)
#pragma unroll
        for (int c = 0; c < 8; ++c) acc[r][c] = (f32x4)(0.f);

    const int arow = tid >> 1;
    const int akh = (tid & 1) * 16;
    const int gm = m0 + arow;
    const int fr = lane & 15;
    const int fq = (lane >> 4) * 8;

    for (int kb = 0; kb < KB; ++kb) {
        const int k0 = kb * 32;
        __syncthreads();
        // ---- stage A ----
        if (ABF) {
            if (gm < M) {
                const unsigned short* Ab = (const unsigned short*)Ap + (size_t)gm * K + k0 + akh;
                *(float4*)&sA[arow][akh]     = *(const float4*)Ab;
                *(float4*)&sA[arow][akh + 8] = *(const float4*)(Ab + 8);
            } else {
                *(float4*)&sA[arow][akh]     = make_float4(0.f, 0.f, 0.f, 0.f);
                *(float4*)&sA[arow][akh + 8] = make_float4(0.f, 0.f, 0.f, 0.f);
            }
        } else if (ZF) {
            if (gm < M) {
                const float* tf = (const float*)Ap + (size_t)gm * K + k0 + akh;
                const float* hf = hres + (size_t)gm * K + k0 + akh;
                float zv[16];
#pragma unroll
                for (int i = 0; i < 16; ++i) {
                    const int c = k0 + akh + i;
                    zv[i] = fmaxf(fmaf(tf[i], sAB[c], sSH[c]), 0.f) + hf[i];
                }
                if (blockIdx.y == 0) {
                    float* zo = zout + (size_t)gm * K + k0 + akh;
#pragma unroll
                    for (int i = 0; i < 16; i += 4)
                        *(float4*)(zo + i) = make_float4(zv[i], zv[i + 1], zv[i + 2], zv[i + 3]);
                }
                us8 p0, p1;
#pragma unroll
                for (int i = 0; i < 8; ++i) { p0[i] = f2b(zv[i]); p1[i] = f2b(zv[8 + i]); }
                *(us8*)&sA[arow][akh]     = p0;
                *(us8*)&sA[arow][akh + 8] = p1;
            } else {
                *(float4*)&sA[arow][akh]     = make_float4(0.f, 0.f, 0.f, 0.f);
                *(float4*)&sA[arow][akh + 8] = make_float4(0.f, 0.f, 0.f, 0.f);
            }
        } else {
            if (gm < M) {
                const float* Af = (const float*)Ap + (size_t)gm * K + k0 + akh;
                const float4 v0 = *(const float4*)(Af);
                const float4 v1 = *(const float4*)(Af + 4);
                const float4 v2 = *(const float4*)(Af + 8);
                const float4 v3 = *(const float4*)(Af + 12);
                const float vals[16] = {v0.x, v0.y, v0.z, v0.w, v1.x, v1.y, v1.z, v1.w,
                                        v2.x, v2.y, v2.z, v2.w, v3.x, v3.y, v3.z, v3.w};
                us8 p0, p1;
#pragma unroll
                for (int i = 0; i < 8; ++i) { p0[i] = f2b(vals[i]); p1[i] = f2b(vals[8 + i]); }
                *(us8*)&sA[arow][akh]     = p0;
                *(us8*)&sA[arow][akh + 8] = p1;
            } else {
                *(float4*)&sA[arow][akh]     = make_float4(0.f, 0.f, 0.f, 0.f);
                *(float4*)&sA[arow][akh + 8] = make_float4(0.f, 0.f, 0.f, 0.f);
            }
        }
        // ---- stage B (row/half indexed to respect padding) ----
#pragma unroll
        for (int p = 0; p < 2; ++p) {
            const int bn = tid >> 1;
            const int bkh = (tid & 1) * 16;
            const unsigned short* src = Wt + ((size_t)(p * KB + kb) * Nn + n0 + bn) * 32 + bkh;
            *(float4*)&sB[p][bn][bkh]     = *(const float4*)src;
            *(float4*)&sB[p][bn][bkh + 8] = *(const float4*)(src + 8);
        }
        __syncthreads();
        // ---- MFMA ----
        const bf16x8 a0 = *(const bf16x8*)&sA[w * 32 + fr][fq];
        const bf16x8 a1 = *(const bf16x8*)&sA[w * 32 + 16 + fr][fq];
#pragma unroll
        for (int c = 0; c < 8; ++c) {
            const bf16x8 bh = *(const bf16x8*)&sB[0][c * 16 + fr][fq];
            const bf16x8 bl = *(const bf16x8*)&sB[1][c * 16 + fr][fq];
            acc[0][c] = __builtin_amdgcn_mfma_f32_16x16x32_bf16(a0, bh, acc[0][c], 0, 0, 0);
            acc[0][c] = __builtin_amdgcn_mfma_f32_16x16x32_bf16(a0, bl, acc[0][c], 0, 0, 0);
            acc[1][c] = __builtin_amdgcn_mfma_f32_16x16x32_bf16(a1, bh, acc[1][c], 0, 0, 0);
            acc[1][c] = __builtin_amdgcn_mfma_f32_16x16x32_bf16(a1, bl, acc[1][c], 0, 0, 0);
        }
    }

    // ---- epilogue ----
    float s[8], q[8];
#pragma unroll
    for (int c = 0; c < 8; ++c) { s[c] = 0.f; q[c] = 0.f; }
    const int crow4 = (lane >> 4) * 4;
#pragma unroll
    for (int r = 0; r < 2; ++r) {
        const int rbase = m0 + w * 32 + r * 16 + crow4;
#pragma unroll
        for (int c = 0; c < 8; ++c) {
            const int gc = n0 + c * 16 + fr;
            const float bb = bias[gc];
#pragma unroll
            for (int reg = 0; reg < 4; ++reg) {
                const int gr = rbase + reg;
                if (gr >= M) continue;
                float o = acc[r][c][reg] + bb;
                if (resid) o += resid[(size_t)gr * Nn + gc];
                if (relu) o = fmaxf(o, 0.f);
                if (statsOut) { s[c] += o; q[c] = fmaf(o, o, q[c]); }
                if (CBF) ((unsigned short*)Cp)[(size_t)gr * Nn + gc] = f2b(o);
                else     ((float*)Cp)[(size_t)gr * Nn + gc] = o;
            }
        }
    }

    if (statsOut) {
#pragma unroll
        for (int c = 0; c < 8; ++c) {
            s[c] += __shfl_xor(s[c], 32, 64); s[c] += __shfl_xor(s[c], 16, 64);
            q[c] += __shfl_xor(q[c], 32, 64); q[c] += __shfl_xor(q[c], 16, 64);
        }
        __syncthreads();
        float* red = (float*)sA;
        if (lane < 16) {
#pragma unroll
            for (int c = 0; c < 8; ++c) {
                red[w * 128 + c * 16 + lane]       = s[c];
                red[512 + w * 128 + c * 16 + lane] = q[c];
            }
        }
        __syncthreads();
        if (tid < 128) {
            const float ss = red[tid] + red[128 + tid] + red[256 + tid] + red[384 + tid];
            const float qq = red[512 + tid] + red[640 + tid] + red[768 + tid] + red[896 + tid];
            atomicAdd(&statsOut[tid], ss);
            atomicAdd(&statsOut[128 + tid], qq);
        }
    }
}

// ---------------------------------------------------------------------------
// fp32 input-projection GEMM, reads x||pe directly.
// ---------------------------------------------------------------------------
__global__ __launch_bounds__(256, 4)
void inproj_kernel(const float* __restrict__ x, const float* __restrict__ pe,
                   const float* __restrict__ W, const float* __restrict__ bias,
                   float* __restrict__ C, unsigned short* __restrict__ Cb, int M)
{
    __shared__ float aT[16][129];
    __shared__ float wsh[16][129];

    const int tid = threadIdx.x;
    const int m0 = blockIdx.x * 128;
    const int rm = (tid >> 4) * 8;
    const int rn = (tid & 15) * 8;

    float acc[8][8];
#pragma unroll
    for (int i = 0; i < 8; ++i)
#pragma unroll
        for (int j = 0; j < 8; ++j) acc[i][j] = 0.f;

    const int lm = tid & 127;
    const int kq = (tid >> 7) * 8;
    const int wk = tid >> 4;
    const int wj = (tid & 15) * 8;

    for (int k0 = 0; k0 < FIN; k0 += 16) {
        {
            const int gm = m0 + lm;
            const int c = k0 + kq;
            if (gm < M) {
                const float* srcp = (c < 64) ? (x + (size_t)gm * 64 + c)
                                             : (pe + (size_t)gm * 16 + (c - 64));
                const float4 v0 = *(const float4*)srcp;
                const float4 v1 = *(const float4*)(srcp + 4);
                aT[kq + 0][lm] = v0.x; aT[kq + 1][lm] = v0.y;
                aT[kq + 2][lm] = v0.z; aT[kq + 3][lm] = v0.w;
                aT[kq + 4][lm] = v1.x; aT[kq + 5][lm] = v1.y;
                aT[kq + 6][lm] = v1.z; aT[kq + 7][lm] = v1.w;
            } else {
#pragma unroll
                for (int i = 0; i < 8; ++i) aT[kq + i][lm] = 0.f;
            }
        }
        {
#pragma unroll
            for (int j = 0; j < 8; ++j)
                wsh[wk][wj + j] = W[(size_t)(k0 + wk) * H + wj + j];
        }
        __syncthreads();
#pragma unroll
        for (int k = 0; k < 16; ++k) {
            const float av[8] = {aT[k][rm], aT[k][rm + 1], aT[k][rm + 2], aT[k][rm + 3],
                                 aT[k][rm + 4], aT[k][rm + 5], aT[k][rm + 6], aT[k][rm + 7]};
            const float bv[8] = {wsh[k][rn], wsh[k][rn + 1], wsh[k][rn + 2], wsh[k][rn + 3],
                                 wsh[k][rn + 4], wsh[k][rn + 5], wsh[k][rn + 6], wsh[k][rn + 7]};
#pragma unroll
            for (int i = 0; i < 8; ++i)
#pragma unroll
                for (int j = 0; j < 8; ++j)
                    acc[i][j] = fmaf(av[i], bv[j], acc[i][j]);
        }
        __syncthreads();
    }

    float bv[8];
#pragma unroll
    for (int j = 0; j < 8; ++j) bv[j] = bias[rn + j];
#pragma unroll
    for (int i = 0; i < 8; ++i) {
        const int gm = m0 + rm + i;
        if (gm >= M) continue;
        float o[8];
#pragma unroll
        for (int j = 0; j < 8; ++j) o[j] = fmaxf(acc[i][j] + bv[j], 0.f);
        *(float4*)&C[(size_t)gm * H + rn]     = make_float4(o[0], o[1], o[2], o[3]);
        *(float4*)&C[(size_t)gm * H + rn + 4] = make_float4(o[4], o[5], o[6], o[7]);
        us8 pk;
#pragma unroll
        for (int j = 0; j < 8; ++j) pk[j] = f2b(o[j]);
        *(us8*)&Cb[(size_t)gm * H + rn] = pk;
    }
}

// ---------------------------------------------------------------------------
// CSR build: histogram -> 3-stage parallel scan -> scatter
// ---------------------------------------------------------------------------
__global__ void hist_kernel(const int* __restrict__ ei, int* __restrict__ deg)
{
    const int e = blockIdx.x * 256 + threadIdx.x;
    if (e < NE) atomicAdd(&deg[ei[NE + e]], 1);
}

__global__ void bsum_kernel(const int* __restrict__ deg, int* __restrict__ bsum)
{
    const int tid = threadIdx.x;
    const int i = blockIdx.x * 256 + tid;
    int v = (i < NN) ? deg[i] : 0;
#pragma unroll
    for (int off = 32; off > 0; off >>= 1) v += __shfl_down(v, off, 64);
    __shared__ int ws[4];
    if ((tid & 63) == 0) ws[tid >> 6] = v;
    __syncthreads();
    if (tid == 0) bsum[blockIdx.x] = ws[0] + ws[1] + ws[2] + ws[3];
}

__global__ void bscan_kernel(int* __restrict__ bsum)
{
    __shared__ int sh[256];
    const int tid = threadIdx.x;
    sh[tid] = (tid < NB) ? bsum[tid] : 0;
    __syncthreads();
    for (int off = 1; off < 256; off <<= 1) {
        const int t = (tid >= off) ? sh[tid - off] : 0;
        __syncthreads();
        sh[tid] += t;
        __syncthreads();
    }
    if (tid < NB) bsum[tid] = (tid == 0) ? 0 : sh[tid - 1];
}

__global__ void bwrite_kernel(const int* __restrict__ deg, const int* __restrict__ boff,
                              int* __restrict__ rowptr, int* __restrict__ cursor)
{
    __shared__ int sh[256];
    const int tid = threadIdx.x;
    const int i = blockIdx.x * 256 + tid;
    const int v = (i < NN) ? deg[i] : 0;
    sh[tid] = v;
    __syncthreads();
    for (int off = 1; off < 256; off <<= 1) {
        const int t = (tid >= off) ? sh[tid - off] : 0;
        __syncthreads();
        sh[tid] += t;
        __syncthreads();
    }
    if (i < NN) {
        const int pos = boff[blockIdx.x] + sh[tid] - v;
        rowptr[i] = pos;
        cursor[i] = pos;
    }
    if (blockIdx.x == 0 && tid == 0) rowptr[NN] = NE;
}

__global__ void scatter_kernel(const int* __restrict__ ei, const float* __restrict__ ea,
                               int* __restrict__ cursor, int* __restrict__ src_s,
                               float* __restrict__ ea_s)
{
    const int e = blockIdx.x * 256 + threadIdx.x;
    if (e >= NE) return;
    const int d = ei[NE + e];
    const int pos = atomicAdd(&cursor[d], 1);
    src_s[pos] = ei[e];
    const float4* sp = (const float4*)&ea[(size_t)e * 16];
    float4* dp = (float4*)&ea_s[(size_t)pos * 16];
    dp[0] = sp[0]; dp[1] = sp[1]; dp[2] = sp[2]; dp[3] = sp[3];
}

// ---------------------------------------------------------------------------
// Aggregation: z = (1+eps)*h + sum relu(h[src] + ea@We + be). One wave/node.
// ---------------------------------------------------------------------------
__global__ __launch_bounds__(256)
void agg_kernel(const float* __restrict__ h, const unsigned short* __restrict__ hb,
                const int* __restrict__ rowptr, const int* __restrict__ src_s,
                const float* __restrict__ ea_s, const float* __restrict__ We,
                const float* __restrict__ be, const float* __restrict__ eps, int l,
                float* __restrict__ z)
{
    const int lane = threadIdx.x & 63;
    const int w = threadIdx.x >> 6;
    const int n = blockIdx.x * 4 + w;
    if (n >= NN) return;

    float w0[16], w1[16];
#pragma unroll
    for (int k = 0; k < 16; ++k) {
        const float2 wv = *(const float2*)&We[k * H + 2 * lane];
        w0[k] = wv.x; w1[k] = wv.y;
    }
    const float2 bev = *(const float2*)&be[2 * lane];

    const int beg = __builtin_amdgcn_readfirstlane(rowptr[n]);
    const int end = __builtin_amdgcn_readfirstlane(rowptr[n + 1]);

    const float e1 = 1.0f + eps[l];
    const float2 hv0 = *(const float2*)&h[(size_t)n * H + 2 * lane];
    float acc0 = e1 * hv0.x;
    float acc1 = e1 * hv0.y;

    for (int i0 = beg; i0 < end; i0 += 8) {
        const int jn = min(8, end - i0);
        int srcs[8];
#pragma unroll
        for (int j = 0; j < 8; ++j)
            srcs[j] = src_s[(i0 + j < end) ? (i0 + j) : (end - 1)];
        unsigned hraw[8];
#pragma unroll
        for (int j = 0; j < 8; ++j)
            hraw[j] = *(const unsigned*)&hb[(size_t)srcs[j] * H + 2 * lane];
#pragma unroll
        for (int j = 0; j < 8; ++j) {
            if (j >= jn) break;
            const float* ar = ea_s + (size_t)(i0 + j) * 16;
            float s0 = bev.x, s1 = bev.y;
#pragma unroll
            for (int k = 0; k < 16; ++k) {
                const float a = ar[k];
                s0 = fmaf(a, w0[k], s0);
                s1 = fmaf(a, w1[k], s1);
            }
            const float hx = __uint_as_float(hraw[j] << 16);
            const float hy = __uint_as_float(hraw[j] & 0xffff0000u);
            acc0 += fmaxf(hx + s0, 0.f);
            acc1 += fmaxf(hy + s1, 0.f);
        }
    }
    *(float2*)&z[(size_t)n * H + 2 * lane] = make_float2(acc0, acc1);
}

// ---------------------------------------------------------------------------
// bn_apply / pool / readout
// ---------------------------------------------------------------------------
__global__ void bn_apply_kernel(const float* __restrict__ u, const float* __restrict__ st,
                                const float* __restrict__ g, const float* __restrict__ b,
                                float* __restrict__ h, unsigned short* __restrict__ hb,
                                float inv_n)
{
    const int i = blockIdx.x * 256 + threadIdx.x;
    const int c = i & (H - 1);
    const float mean = st[c] * inv_n;
    const float var = st[H + c] * inv_n - mean * mean;
    const float a = g[c] * rsqrtf(var + BN_EPS);
    const float s = fmaf(-mean, a, b[c]);
    const float v = fmaf(u[i], a, s);
    h[i] = v;
    hb[i] = f2b(v);
}

__global__ void pool_kernel(const float* __restrict__ h, const int* __restrict__ batch,
                            float* __restrict__ pool, float* __restrict__ cnt, int n)
{
    const int c = threadIdx.x & (H - 1);
    const int half = threadIdx.x >> 7;
    const int r0 = blockIdx.x * 256 + half * 128;
    if (r0 >= n) return;
    const int rend = min(r0 + 128, n);
    int gprev = batch[r0];
    float acc = 0.f;
    int run = 0;
    for (int r = r0; r < rend; ++r) {
        const int g = batch[r];
        if (g != gprev) {
            atomicAdd(&pool[gprev * H + c], acc);
            if (c == 0) atomicAdd(&cnt[gprev], (float)run);
            acc = 0.f; run = 0; gprev = g;
        }
        acc += h[(size_t)r * H + c];
        run++;
    }
    atomicAdd(&pool[gprev * H + c], acc);
    if (c == 0) atomicAdd(&cnt[gprev], (float)run);
}

__global__ void readout_kernel(const float* __restrict__ pool, const float* __restrict__ cnt,
                               const float* __restrict__ Wr1, const float* __restrict__ br1,
                               const float* __restrict__ Wr2, const float* __restrict__ br2,
                               float* __restrict__ out)
{
    __shared__ float hg[H];
    __shared__ float r1[H];
    const int g = blockIdx.x;
    const int j = threadIdx.x;
    hg[j] = pool[g * H + j] / fmaxf(cnt[g], 1.0f);
    __syncthreads();
    float acc = br1[j];
    for (int k = 0; k < H; ++k) acc = fmaf(hg[k], Wr1[k * H + j], acc);
    r1[j] = fmaxf(acc, 0.f);
    __syncthreads();
    if (j < NCLS) {
        float o = br2[j];
        for (int k = 0; k < H; ++k) o = fmaf(r1[k], Wr2[k * NCLS + j], o);
        out[g * NCLS + j] = o;
    }
}

// ---------------------------------------------------------------------------
extern "C" void kernel_launch(void* const* d_in, const int* in_sizes, int n_in,
                              void* d_out, int out_size, void* d_ws, size_t ws_size,
                              hipStream_t stream)
{
    const float* x       = (const float*)d_in[0];
    const float* pe      = (const float*)d_in[1];
    const int*   ei      = (const int*)d_in[2];
    const float* ea      = (const float*)d_in[3];
    const int*   batch   = (const int*)d_in[4];
    const float* W_in    = (const float*)d_in[5];
    const float* b_in    = (const float*)d_in[6];
    const float* We_edge = (const float*)d_in[7];
    const float* be_edge = (const float*)d_in[8];
    const float* eps     = (const float*)d_in[9];
    const float* W1g     = (const float*)d_in[10];
    const float* b1g     = (const float*)d_in[11];
    const float* W2g     = (const float*)d_in[12];
    const float* b2g     = (const float*)d_in[13];
    const float* bn1g    = (const float*)d_in[14];
    const float* bn1b    = (const float*)d_in[15];
    const float* W1f     = (const float*)d_in[16];
    const float* b1f     = (const float*)d_in[17];
    const float* W2f     = (const float*)d_in[18];
    const float* b2f     = (const float*)d_in[19];
    const float* bn2g    = (const float*)d_in[20];
    const float* bn2b    = (const float*)d_in[21];
    const float* Wr1     = (const float*)d_in[22];
    const float* br1     = (const float*)d_in[23];
    const float* Wr2     = (const float*)d_in[24];
    const float* br2     = (const float*)d_in[25];
    float* out = (float*)d_out;

    const size_t NH = (size_t)NN * H;
    float* hbuf  = (float*)d_ws;                     // [NN,H] fp32
    float* zbuf  = hbuf + NH;                        // [NN,H] fp32
    float* tbuf  = zbuf + NH;                        // [NN,H] fp32
    unsigned short* z1 = (unsigned short*)(tbuf + NH);  // [NN,H2] bf16
    // contiguous zero-init block: [deg NN][stats 2048][pool NG*H][cnt NG]
    int*   deg   = (int*)(z1 + (size_t)NN * H2);
    float* stats = (float*)(deg + NN);               // [4 layers][2 slabs][256]
    float* pool  = stats + 2048;                     // [NG,H]
    float* cnt   = pool + NG * H;                    // [NG]
    int*   rowptr = (int*)(cnt + NG);                // [NN+1]
    int*   cursor = rowptr + NN + 1;                 // [NN]
    int*   bsum   = cursor + NN;                     // [256]
    int*   src_s  = bsum + 256;                      // [NE]
    float* ea_s   = (float*)(src_s + NE);            // [NE,16]
    unsigned short* hb = (unsigned short*)(ea_s + (size_t)NE * 16);  // [NN,H] bf16
    unsigned short* wt = hb + NH;                    // 16 matrices x 2*K*N
    unsigned short* wt1g = wt;
    unsigned short* wt2g = wt + 4 * 65536;
    unsigned short* wt1f = wt + 8 * 65536;
    unsigned short* wt2f = wt + 12 * 65536;

    const dim3 blk(256);
    const dim3 mg1((NN + 127) / 128, 1);
    const dim3 mg2((NN + 127) / 128, 2);
    const int ew_grid = (int)(NH / 256);
    const float inv_n = 1.0f / (float)NN;
    const size_t zero_bytes = (size_t)(NN + 2048 + NG * H + NG) * 4;

    // ---- weight prep (one dispatch) ----
    wprep_all<<<2048, blk, 0, stream>>>(W1g, W2g, W1f, W2f, wt);

    // ---- zero-init + CSR build (parallel scan) ----
    hipMemsetAsync(deg, 0, zero_bytes, stream);
    hist_kernel<<<(NE + 255) / 256, blk, 0, stream>>>(ei, deg);
    bsum_kernel<<<NB, blk, 0, stream>>>(deg, bsum);
    bscan_kernel<<<1, blk, 0, stream>>>(bsum);
    bwrite_kernel<<<NB, blk, 0, stream>>>(deg, bsum, rowptr, cursor);
    scatter_kernel<<<(NE + 255) / 256, blk, 0, stream>>>(ei, ea, cursor, src_s, ea_s);

    // ---- input projection ----
    inproj_kernel<<<mg1, blk, 0, stream>>>(x, pe, W_in, b_in, hbuf, hb, NN);

    for (int l = 0; l < 4; ++l) {
        float* s1 = stats + (size_t)l * 512;
        float* s2 = s1 + 256;

        agg_kernel<<<(NN + 3) / 4, blk, 0, stream>>>(hbuf, hb, rowptr, src_s, ea_s,
                                                     We_edge + (size_t)l * 16 * H,
                                                     be_edge + (size_t)l * H, eps, l, zbuf);

        mgemm<false, true, false><<<mg2, blk, 0, stream>>>(
            zbuf, wt1g + (size_t)l * 65536, b1g + (size_t)l * H2, nullptr, z1,
            NN, 128, 256, 1, nullptr, nullptr, nullptr, nullptr, nullptr, nullptr, inv_n);
        mgemm<true, false, false><<<mg1, blk, 0, stream>>>(
            z1, wt2g + (size_t)l * 65536, b2g + (size_t)l * H, nullptr, tbuf,
            NN, 256, 128, 0, s1, nullptr, nullptr, nullptr, nullptr, nullptr, inv_n);

        mgemm<false, true, true><<<mg2, blk, 0, stream>>>(
            tbuf, wt1f + (size_t)l * 65536, b1f + (size_t)l * H2, nullptr, z1,
            NN, 128, 256, 1, nullptr, s1, bn1g + (size_t)l * H, bn1b + (size_t)l * H,
            hbuf, zbuf, inv_n);

        mgemm<true, false, false><<<mg1, blk, 0, stream>>>(
            z1, wt2f + (size_t)l * 65536, b2f + (size_t)l * H, zbuf, tbuf,
            NN, 256, 128, 0, s2, nullptr, nullptr, nullptr, nullptr, nullptr, inv_n);

        bn_apply_kernel<<<ew_grid, blk, 0, stream>>>(tbuf, s2, bn2g + (size_t)l * H,
                                                     bn2b + (size_t)l * H, hbuf, hb, inv_n);
    }

    pool_kernel<<<(NN + 255) / 256, blk, 0, stream>>>(hbuf, batch, pool, cnt, NN);
    readout_kernel<<<NG, H, 0, stream>>>(pool, cnt, Wr1, br1, Wr2, br2, out);
}

// Round 7
// 1146.463 us; speedup vs baseline: 2.8596x; 1.1506x over previous
//
#include <hip/hip_runtime.h>
#include <hip/hip_bf16.h>

#define NN 50000
#define NE 800000
#define FIN 80
#define H 128
#define H2 256
#define NG 64
#define NCLS 10
#define BN_EPS 1e-5f
#define NB 196    // ceil(NN/256)
#define LDK 40    // padded LDS leading dim (shorts)
#define LDY 264   // padded y leading dim (shorts)

typedef __attribute__((ext_vector_type(8))) short bf16x8;
typedef __attribute__((ext_vector_type(8))) unsigned short us8;
typedef __attribute__((ext_vector_type(4))) float f32x4;

__device__ __forceinline__ unsigned short f2b(float f) {
    __hip_bfloat16 h = __float2bfloat16(f);   // RNE
    return *(unsigned short*)&h;
}
__device__ __forceinline__ float b2f(unsigned short u) {
    unsigned v = (unsigned)u << 16;
    return __uint_as_float(v);
}

// ---------------------------------------------------------------------------
// Weight prep: W[L][K][Nn] fp32 -> {hi,lo} bf16 planes, k-blocked:
// dst[l][ ((p*KB + kb)*Nn + n)*32 + kk ]
// ---------------------------------------------------------------------------
__global__ void wprep_all(const float* __restrict__ W1g, const float* __restrict__ W2g,
                          const float* __restrict__ W1f, const float* __restrict__ W2f,
                          unsigned short* __restrict__ wt)
{
    const int idx = blockIdx.x * 256 + threadIdx.x;   // grid = 2048*256
    const int m = idx >> 17;
    const int r = idx & 131071;
    const float* W;
    unsigned short* Wt;
    int K, Nn;
    if (m == 0)      { W = W1g; Wt = wt;              K = 128; Nn = 256; }
    else if (m == 1) { W = W2g; Wt = wt + 4 * 65536;  K = 256; Nn = 128; }
    else if (m == 2) { W = W1f; Wt = wt + 8 * 65536;  K = 128; Nn = 256; }
    else             { W = W2f; Wt = wt + 12 * 65536; K = 256; Nn = 128; }
    const int per = K * Nn;        // 32768
    const int l = r / per;
    const int rr = r - l * per;
    const int k = rr / Nn;
    const int n = rr - k * Nn;
    const float wv = W[r];
    const unsigned short hi = f2b(wv);
    const unsigned short lo = f2b(wv - b2f(hi));
    const int KB = K >> 5;
    const int kb = k >> 5, kk = k & 31;
    unsigned short* base = Wt + (size_t)l * 2 * per;
    base[((size_t)(0 * KB + kb) * Nn + n) * 32 + kk] = hi;
    base[((size_t)(1 * KB + kb) * Nn + n) * 32 + kk] = lo;
}

// ---------------------------------------------------------------------------
// Fused MLP pair: C[M,128] = (relu(A[M,128] @ W1 + b1)) @ W2 + b2 (+resid)
// W1: 128->256, W2: 256->128, both hi/lo bf16 split. One block = 128 rows.
// Hidden y kept in LDS (bf16); B-fragments loaded straight from L2-hot Wt.
// ZF: A is computed in staging as z = relu(bn1(t)) + h (t=Ain, h=hres, bn
//     from statsIn shadows); epilogue adds recomputed z as residual.
// statsOut: per-column sum/sumsq of C, atomics into 8 shadow slabs.
// ---------------------------------------------------------------------------
template<bool ZF>
__global__ __launch_bounds__(256, 2)
void gemm_pair(const float* __restrict__ Ain, const float* __restrict__ hres,
               const unsigned short* __restrict__ Wt1, const unsigned short* __restrict__ Wt2,
               const float* __restrict__ b1, const float* __restrict__ b2,
               const float* __restrict__ statsIn, const float* __restrict__ bng,
               const float* __restrict__ bnb, float* __restrict__ statsOut,
               float* __restrict__ Cout, float inv_n, int M)
{
    __shared__ unsigned short sA[128][LDK];    // 10.2 KB
    __shared__ unsigned short sy[128][LDY];    // 67.6 KB
    __shared__ float sAB[128];
    __shared__ float sSH[128];

    const int tid = threadIdx.x;
    const int m0 = blockIdx.x * 128;
    const int lane = tid & 63;
    const int w = tid >> 6;
    const int fr = lane & 15;
    const int fq = (lane >> 4) * 8;
    const int crow4 = (lane >> 4) * 4;
    const int arow = tid >> 1;
    const int akh = (tid & 1) * 16;
    const int gm = m0 + arow;

    if (ZF) {
        if (tid < 128) {
            float su = 0.f, qu = 0.f;
#pragma unroll
            for (int s = 0; s < 8; ++s) {
                su += statsIn[s * 256 + tid];
                qu += statsIn[s * 256 + 128 + tid];
            }
            const float mean = su * inv_n;
            const float var = qu * inv_n - mean * mean;
            const float a = bng[tid] * rsqrtf(var + BN_EPS);
            sAB[tid] = a;
            sSH[tid] = fmaf(-mean, a, bnb[tid]);
        }
    }

    // ---------------- stage 1: y = relu(A @ W1 + b1) ----------------
    f32x4 acc1[2][16];
#pragma unroll
    for (int r = 0; r < 2; ++r)
#pragma unroll
        for (int c = 0; c < 16; ++c) acc1[r][c] = (f32x4)(0.f);

    for (int kb = 0; kb < 4; ++kb) {
        __syncthreads();   // covers sAB init (kb=0) and sA reuse
        if (gm < M) {
            const float* tf = Ain + (size_t)gm * 128 + kb * 32 + akh;
            float zv[16];
            if (ZF) {
                const float* hf = hres + (size_t)gm * 128 + kb * 32 + akh;
#pragma unroll
                for (int i = 0; i < 16; ++i) {
                    const int c = kb * 32 + akh + i;
                    zv[i] = fmaxf(fmaf(tf[i], sAB[c], sSH[c]), 0.f) + hf[i];
                }
            } else {
#pragma unroll
                for (int i = 0; i < 16; ++i) zv[i] = tf[i];
            }
            us8 p0, p1;
#pragma unroll
            for (int i = 0; i < 8; ++i) { p0[i] = f2b(zv[i]); p1[i] = f2b(zv[8 + i]); }
            *(us8*)&sA[arow][akh]     = p0;
            *(us8*)&sA[arow][akh + 8] = p1;
        } else {
            *(float4*)&sA[arow][akh]     = make_float4(0.f, 0.f, 0.f, 0.f);
            *(float4*)&sA[arow][akh + 8] = make_float4(0.f, 0.f, 0.f, 0.f);
        }
        __syncthreads();
        const bf16x8 a0 = *(const bf16x8*)&sA[w * 32 + fr][fq];
        const bf16x8 a1 = *(const bf16x8*)&sA[w * 32 + 16 + fr][fq];
#pragma unroll
        for (int ct = 0; ct < 16; ++ct) {
            const bf16x8 bh = *(const bf16x8*)&Wt1[((size_t)(kb) * 256 + ct * 16 + fr) * 32 + fq];
            const bf16x8 bl = *(const bf16x8*)&Wt1[((size_t)(4 + kb) * 256 + ct * 16 + fr) * 32 + fq];
            acc1[0][ct] = __builtin_amdgcn_mfma_f32_16x16x32_bf16(a0, bh, acc1[0][ct], 0, 0, 0);
            acc1[0][ct] = __builtin_amdgcn_mfma_f32_16x16x32_bf16(a0, bl, acc1[0][ct], 0, 0, 0);
            acc1[1][ct] = __builtin_amdgcn_mfma_f32_16x16x32_bf16(a1, bh, acc1[1][ct], 0, 0, 0);
            acc1[1][ct] = __builtin_amdgcn_mfma_f32_16x16x32_bf16(a1, bl, acc1[1][ct], 0, 0, 0);
        }
    }
    // write y (bias + relu + bf16) into LDS
#pragma unroll
    for (int ct = 0; ct < 16; ++ct) {
        const float bb = b1[ct * 16 + fr];
#pragma unroll
        for (int r = 0; r < 2; ++r) {
            const int row0 = w * 32 + r * 16 + crow4;
#pragma unroll
            for (int reg = 0; reg < 4; ++reg) {
                const float o = fmaxf(acc1[r][ct][reg] + bb, 0.f);
                sy[row0 + reg][ct * 16 + fr] = f2b(o);
            }
        }
    }
    __syncthreads();

    // ---------------- stage 2: C = y @ W2 + b2 (+resid) ----------------
    f32x4 acc2[2][8];
#pragma unroll
    for (int r = 0; r < 2; ++r)
#pragma unroll
        for (int c = 0; c < 8; ++c) acc2[r][c] = (f32x4)(0.f);

    for (int kb = 0; kb < 8; ++kb) {
        const bf16x8 ya0 = *(const bf16x8*)&sy[w * 32 + fr][kb * 32 + fq];
        const bf16x8 ya1 = *(const bf16x8*)&sy[w * 32 + 16 + fr][kb * 32 + fq];
#pragma unroll
        for (int ct = 0; ct < 8; ++ct) {
            const bf16x8 bh = *(const bf16x8*)&Wt2[((size_t)(kb) * 128 + ct * 16 + fr) * 32 + fq];
            const bf16x8 bl = *(const bf16x8*)&Wt2[((size_t)(8 + kb) * 128 + ct * 16 + fr) * 32 + fq];
            acc2[0][ct] = __builtin_amdgcn_mfma_f32_16x16x32_bf16(ya0, bh, acc2[0][ct], 0, 0, 0);
            acc2[0][ct] = __builtin_amdgcn_mfma_f32_16x16x32_bf16(ya0, bl, acc2[0][ct], 0, 0, 0);
            acc2[1][ct] = __builtin_amdgcn_mfma_f32_16x16x32_bf16(ya1, bh, acc2[1][ct], 0, 0, 0);
            acc2[1][ct] = __builtin_amdgcn_mfma_f32_16x16x32_bf16(ya1, bl, acc2[1][ct], 0, 0, 0);
        }
    }

    // ---------------- epilogue ----------------
    float s[8], q[8];
#pragma unroll
    for (int c = 0; c < 8; ++c) { s[c] = 0.f; q[c] = 0.f; }
#pragma unroll
    for (int r = 0; r < 2; ++r) {
        const int rbase = m0 + w * 32 + r * 16 + crow4;
#pragma unroll
        for (int ct = 0; ct < 8; ++ct) {
            const int gc = ct * 16 + fr;
            const float bb = b2[gc];
#pragma unroll
            for (int reg = 0; reg < 4; ++reg) {
                const int gr = rbase + reg;
                if (gr >= M) continue;
                float o = acc2[r][ct][reg] + bb;
                if (ZF) {
                    const float tv = Ain[(size_t)gr * 128 + gc];
                    const float hv = hres[(size_t)gr * 128 + gc];
                    o += fmaxf(fmaf(tv, sAB[gc], sSH[gc]), 0.f) + hv;
                }
                s[ct] += o;
                q[ct] = fmaf(o, o, q[ct]);
                Cout[(size_t)gr * 128 + gc] = o;
            }
        }
    }

    // stats reduce -> 8 shadow slabs
#pragma unroll
    for (int c = 0; c < 8; ++c) {
        s[c] += __shfl_xor(s[c], 32, 64); s[c] += __shfl_xor(s[c], 16, 64);
        q[c] += __shfl_xor(q[c], 32, 64); q[c] += __shfl_xor(q[c], 16, 64);
    }
    __syncthreads();
    float* red = (float*)sA;
    if (lane < 16) {
#pragma unroll
        for (int c = 0; c < 8; ++c) {
            red[w * 128 + c * 16 + lane]       = s[c];
            red[512 + w * 128 + c * 16 + lane] = q[c];
        }
    }
    __syncthreads();
    if (tid < 128) {
        const float ss = red[tid] + red[128 + tid] + red[256 + tid] + red[384 + tid];
        const float qq = red[512 + tid] + red[640 + tid] + red[768 + tid] + red[896 + tid];
        float* slab = statsOut + (blockIdx.x & 7) * 256;
        atomicAdd(&slab[tid], ss);
        atomicAdd(&slab[128 + tid], qq);
    }
}

// ---------------------------------------------------------------------------
// fp32 input-projection GEMM, reads x||pe directly.
// ---------------------------------------------------------------------------
__global__ __launch_bounds__(256, 4)
void inproj_kernel(const float* __restrict__ x, const float* __restrict__ pe,
                   const float* __restrict__ W, const float* __restrict__ bias,
                   float* __restrict__ C, unsigned short* __restrict__ Cb, int M)
{
    __shared__ float aT[16][129];
    __shared__ float wsh[16][129];

    const int tid = threadIdx.x;
    const int m0 = blockIdx.x * 128;
    const int rm = (tid >> 4) * 8;
    const int rn = (tid & 15) * 8;

    float acc[8][8];
#pragma unroll
    for (int i = 0; i < 8; ++i)
#pragma unroll
        for (int j = 0; j < 8; ++j) acc[i][j] = 0.f;

    const int lm = tid & 127;
    const int kq = (tid >> 7) * 8;
    const int wk = tid >> 4;
    const int wj = (tid & 15) * 8;

    for (int k0 = 0; k0 < FIN; k0 += 16) {
        {
            const int gm = m0 + lm;
            const int c = k0 + kq;
            if (gm < M) {
                const float* srcp = (c < 64) ? (x + (size_t)gm * 64 + c)
                                             : (pe + (size_t)gm * 16 + (c - 64));
                const float4 v0 = *(const float4*)srcp;
                const float4 v1 = *(const float4*)(srcp + 4);
                aT[kq + 0][lm] = v0.x; aT[kq + 1][lm] = v0.y;
                aT[kq + 2][lm] = v0.z; aT[kq + 3][lm] = v0.w;
                aT[kq + 4][lm] = v1.x; aT[kq + 5][lm] = v1.y;
                aT[kq + 6][lm] = v1.z; aT[kq + 7][lm] = v1.w;
            } else {
#pragma unroll
                for (int i = 0; i < 8; ++i) aT[kq + i][lm] = 0.f;
            }
        }
        {
#pragma unroll
            for (int j = 0; j < 8; ++j)
                wsh[wk][wj + j] = W[(size_t)(k0 + wk) * H + wj + j];
        }
        __syncthreads();
#pragma unroll
        for (int k = 0; k < 16; ++k) {
            const float av[8] = {aT[k][rm], aT[k][rm + 1], aT[k][rm + 2], aT[k][rm + 3],
                                 aT[k][rm + 4], aT[k][rm + 5], aT[k][rm + 6], aT[k][rm + 7]};
            const float bv[8] = {wsh[k][rn], wsh[k][rn + 1], wsh[k][rn + 2], wsh[k][rn + 3],
                                 wsh[k][rn + 4], wsh[k][rn + 5], wsh[k][rn + 6], wsh[k][rn + 7]};
#pragma unroll
            for (int i = 0; i < 8; ++i)
#pragma unroll
                for (int j = 0; j < 8; ++j)
                    acc[i][j] = fmaf(av[i], bv[j], acc[i][j]);
        }
        __syncthreads();
    }

    float bv[8];
#pragma unroll
    for (int j = 0; j < 8; ++j) bv[j] = bias[rn + j];
#pragma unroll
    for (int i = 0; i < 8; ++i) {
        const int gm = m0 + rm + i;
        if (gm >= M) continue;
        float o[8];
#pragma unroll
        for (int j = 0; j < 8; ++j) o[j] = fmaxf(acc[i][j] + bv[j], 0.f);
        *(float4*)&C[(size_t)gm * H + rn]     = make_float4(o[0], o[1], o[2], o[3]);
        *(float4*)&C[(size_t)gm * H + rn + 4] = make_float4(o[4], o[5], o[6], o[7]);
        us8 pk;
#pragma unroll
        for (int j = 0; j < 8; ++j) pk[j] = f2b(o[j]);
        *(us8*)&Cb[(size_t)gm * H + rn] = pk;
    }
}

// ---------------------------------------------------------------------------
// CSR build: histogram -> parallel scan -> index scatter -> coalesced gather
// ---------------------------------------------------------------------------
__global__ void hist_kernel(const int* __restrict__ ei, int* __restrict__ deg)
{
    const int e = blockIdx.x * 256 + threadIdx.x;
    if (e < NE) atomicAdd(&deg[ei[NE + e]], 1);
}

__global__ void bsum_kernel(const int* __restrict__ deg, int* __restrict__ bsum)
{
    const int tid = threadIdx.x;
    const int i = blockIdx.x * 256 + tid;
    int v = (i < NN) ? deg[i] : 0;
#pragma unroll
    for (int off = 32; off > 0; off >>= 1) v += __shfl_down(v, off, 64);
    __shared__ int ws[4];
    if ((tid & 63) == 0) ws[tid >> 6] = v;
    __syncthreads();
    if (tid == 0) bsum[blockIdx.x] = ws[0] + ws[1] + ws[2] + ws[3];
}

__global__ void bscan_kernel(int* __restrict__ bsum)
{
    __shared__ int sh[256];
    const int tid = threadIdx.x;
    sh[tid] = (tid < NB) ? bsum[tid] : 0;
    __syncthreads();
    for (int off = 1; off < 256; off <<= 1) {
        const int t = (tid >= off) ? sh[tid - off] : 0;
        __syncthreads();
        sh[tid] += t;
        __syncthreads();
    }
    if (tid < NB) bsum[tid] = (tid == 0) ? 0 : sh[tid - 1];
}

__global__ void bwrite_kernel(const int* __restrict__ deg, const int* __restrict__ boff,
                              int* __restrict__ rowptr, int* __restrict__ cursor)
{
    __shared__ int sh[256];
    const int tid = threadIdx.x;
    const int i = blockIdx.x * 256 + tid;
    const int v = (i < NN) ? deg[i] : 0;
    sh[tid] = v;
    __syncthreads();
    for (int off = 1; off < 256; off <<= 1) {
        const int t = (tid >= off) ? sh[tid - off] : 0;
        __syncthreads();
        sh[tid] += t;
        __syncthreads();
    }
    if (i < NN) {
        const int pos = boff[blockIdx.x] + sh[tid] - v;
        rowptr[i] = pos;
        cursor[i] = pos;
    }
    if (blockIdx.x == 0 && tid == 0) rowptr[NN] = NE;
}

// phase A: 8 B scatters only (pos index + src)
__global__ void scat_idx(const int* __restrict__ ei, int* __restrict__ cursor,
                         int* __restrict__ src_s, int* __restrict__ perm)
{
    const int e = blockIdx.x * 256 + threadIdx.x;
    if (e >= NE) return;
    const int pos = atomicAdd(&cursor[ei[NE + e]], 1);
    src_s[pos] = ei[e];
    perm[pos] = e;
}

// phase B: gather ea rows, coalesced writes (4 threads = 1 edge)
__global__ void gather_ea(const float* __restrict__ ea, const int* __restrict__ perm,
                          float* __restrict__ ea_s)
{
    const int idx = blockIdx.x * 256 + threadIdx.x;    // grid = NE*4/256
    const int pos = idx >> 2;
    const int qd = idx & 3;
    const int e = perm[pos];
    *(float4*)&ea_s[(size_t)pos * 16 + qd * 4] = *(const float4*)&ea[(size_t)e * 16 + qd * 4];
}

// ---------------------------------------------------------------------------
// Aggregation: z = (1+eps)*h + sum relu(h[src] + ea@We + be). One wave/node.
// 16 gathers in flight (avg degree).
// ---------------------------------------------------------------------------
__global__ __launch_bounds__(256)
void agg_kernel(const float* __restrict__ h, const unsigned short* __restrict__ hb,
                const int* __restrict__ rowptr, const int* __restrict__ src_s,
                const float* __restrict__ ea_s, const float* __restrict__ We,
                const float* __restrict__ be, const float* __restrict__ eps, int l,
                float* __restrict__ z)
{
    const int lane = threadIdx.x & 63;
    const int w = threadIdx.x >> 6;
    const int n = blockIdx.x * 4 + w;
    if (n >= NN) return;

    float w0[16], w1[16];
#pragma unroll
    for (int k = 0; k < 16; ++k) {
        const float2 wv = *(const float2*)&We[k * H + 2 * lane];
        w0[k] = wv.x; w1[k] = wv.y;
    }
    const float2 bev = *(const float2*)&be[2 * lane];

    const int beg = __builtin_amdgcn_readfirstlane(rowptr[n]);
    const int end = __builtin_amdgcn_readfirstlane(rowptr[n + 1]);

    const float e1 = 1.0f + eps[l];
    const float2 hv0 = *(const float2*)&h[(size_t)n * H + 2 * lane];
    float acc0 = e1 * hv0.x;
    float acc1 = e1 * hv0.y;

    for (int i0 = beg; i0 < end; i0 += 16) {
        const int jn = min(16, end - i0);
        int srcs[16];
#pragma unroll
        for (int j = 0; j < 16; ++j)
            srcs[j] = src_s[(i0 + j < end) ? (i0 + j) : (end - 1)];
        unsigned hraw[16];
#pragma unroll
        for (int j = 0; j < 16; ++j)
            hraw[j] = *(const unsigned*)&hb[(size_t)srcs[j] * H + 2 * lane];
#pragma unroll
        for (int j = 0; j < 16; ++j) {
            if (j >= jn) break;
            const float* ar = ea_s + (size_t)(i0 + j) * 16;
            float s0 = bev.x, s1 = bev.y;
#pragma unroll
            for (int k = 0; k < 16; ++k) {
                const float a = ar[k];
                s0 = fmaf(a, w0[k], s0);
                s1 = fmaf(a, w1[k], s1);
            }
            const float hx = __uint_as_float(hraw[j] << 16);
            const float hy = __uint_as_float(hraw[j] & 0xffff0000u);
            acc0 += fmaxf(hx + s0, 0.f);
            acc1 += fmaxf(hy + s1, 0.f);
        }
    }
    *(float2*)&z[(size_t)n * H + 2 * lane] = make_float2(acc0, acc1);
}

// ---------------------------------------------------------------------------
// bn_apply (8-shadow stats) / pool / readout
// ---------------------------------------------------------------------------
__global__ void bn_apply_kernel(const float* __restrict__ u, const float* __restrict__ st,
                                const float* __restrict__ g, const float* __restrict__ b,
                                float* __restrict__ h, unsigned short* __restrict__ hb,
                                float inv_n)
{
    const int i = blockIdx.x * 256 + threadIdx.x;
    const int c = i & (H - 1);
    float su = 0.f, qu = 0.f;
#pragma unroll
    for (int s = 0; s < 8; ++s) { su += st[s * 256 + c]; qu += st[s * 256 + 128 + c]; }
    const float mean = su * inv_n;
    const float var = qu * inv_n - mean * mean;
    const float a = g[c] * rsqrtf(var + BN_EPS);
    const float sh = fmaf(-mean, a, b[c]);
    const float v = fmaf(u[i], a, sh);
    h[i] = v;
    hb[i] = f2b(v);
}

__global__ void pool_kernel(const float* __restrict__ h, const int* __restrict__ batch,
                            float* __restrict__ pool, float* __restrict__ cnt, int n)
{
    const int c = threadIdx.x & (H - 1);
    const int half = threadIdx.x >> 7;
    const int r0 = blockIdx.x * 256 + half * 128;
    if (r0 >= n) return;
    const int rend = min(r0 + 128, n);
    int gprev = batch[r0];
    float acc = 0.f;
    int run = 0;
    for (int r = r0; r < rend; ++r) {
        const int g = batch[r];
        if (g != gprev) {
            atomicAdd(&pool[gprev * H + c], acc);
            if (c == 0) atomicAdd(&cnt[gprev], (float)run);
            acc = 0.f; run = 0; gprev = g;
        }
        acc += h[(size_t)r * H + c];
        run++;
    }
    atomicAdd(&pool[gprev * H + c], acc);
    if (c == 0) atomicAdd(&cnt[gprev], (float)run);
}

__global__ void readout_kernel(const float* __restrict__ pool, const float* __restrict__ cnt,
                               const float* __restrict__ Wr1, const float* __restrict__ br1,
                               const float* __restrict__ Wr2, const float* __restrict__ br2,
                               float* __restrict__ out)
{
    __shared__ float hg[H];
    __shared__ float r1[H];
    const int g = blockIdx.x;
    const int j = threadIdx.x;
    hg[j] = pool[g * H + j] / fmaxf(cnt[g], 1.0f);
    __syncthreads();
    float acc = br1[j];
    for (int k = 0; k < H; ++k) acc = fmaf(hg[k], Wr1[k * H + j], acc);
    r1[j] = fmaxf(acc, 0.f);
    __syncthreads();
    if (j < NCLS) {
        float o = br2[j];
        for (int k = 0; k < H; ++k) o = fmaf(r1[k], Wr2[k * NCLS + j], o);
        out[g * NCLS + j] = o;
    }
}

// ---------------------------------------------------------------------------
extern "C" void kernel_launch(void* const* d_in, const int* in_sizes, int n_in,
                              void* d_out, int out_size, void* d_ws, size_t ws_size,
                              hipStream_t stream)
{
    const float* x       = (const float*)d_in[0];
    const float* pe      = (const float*)d_in[1];
    const int*   ei      = (const int*)d_in[2];
    const float* ea      = (const float*)d_in[3];
    const int*   batch   = (const int*)d_in[4];
    const float* W_in    = (const float*)d_in[5];
    const float* b_in    = (const float*)d_in[6];
    const float* We_edge = (const float*)d_in[7];
    const float* be_edge = (const float*)d_in[8];
    const float* eps     = (const float*)d_in[9];
    const float* W1g     = (const float*)d_in[10];
    const float* b1g     = (const float*)d_in[11];
    const float* W2g     = (const float*)d_in[12];
    const float* b2g     = (const float*)d_in[13];
    const float* bn1g    = (const float*)d_in[14];
    const float* bn1b    = (const float*)d_in[15];
    const float* W1f     = (const float*)d_in[16];
    const float* b1f     = (const float*)d_in[17];
    const float* W2f     = (const float*)d_in[18];
    const float* b2f     = (const float*)d_in[19];
    const float* bn2g    = (const float*)d_in[20];
    const float* bn2b    = (const float*)d_in[21];
    const float* Wr1     = (const float*)d_in[22];
    const float* br1     = (const float*)d_in[23];
    const float* Wr2     = (const float*)d_in[24];
    const float* br2     = (const float*)d_in[25];
    float* out = (float*)d_out;

    const size_t NH = (size_t)NN * H;
    float* hbuf  = (float*)d_ws;                     // [NN,H] fp32
    float* zbuf  = hbuf + NH;                        // [NN,H] fp32
    float* tbuf  = zbuf + NH;                        // [NN,H] fp32
    int*   perm  = (int*)(tbuf + NH);                // [NE]
    // contiguous zero block: [deg NN][stats 16384][pool NG*H][cnt NG]
    int*   deg   = perm + NE;
    float* stats = (float*)(deg + NN);               // 4 layers x 2 slabs x 2048
    float* pool  = stats + 16384;                    // [NG,H]
    float* cnt   = pool + NG * H;                    // [NG]
    int*   rowptr = (int*)(cnt + NG);                // [NN+1]
    int*   cursor = rowptr + NN + 1;                 // [NN]
    int*   bsum   = cursor + NN;                     // [256]
    int*   src_s  = bsum + 256;                      // [NE]
    float* ea_s   = (float*)(src_s + NE);            // [NE,16]
    unsigned short* hb = (unsigned short*)(ea_s + (size_t)NE * 16);  // [NN,H] bf16
    unsigned short* wt = hb + NH;                    // 16 matrices x 2*K*N
    unsigned short* wt1g = wt;
    unsigned short* wt2g = wt + 4 * 65536;
    unsigned short* wt1f = wt + 8 * 65536;
    unsigned short* wt2f = wt + 12 * 65536;

    const dim3 blk(256);
    const dim3 mg1((NN + 127) / 128, 1);
    const int ew_grid = (int)(NH / 256);
    const float inv_n = 1.0f / (float)NN;
    const size_t zero_bytes = (size_t)(NN + 16384 + NG * H + NG) * 4;

    // ---- weight prep ----
    wprep_all<<<2048, blk, 0, stream>>>(W1g, W2g, W1f, W2f, wt);

    // ---- zero-init + CSR build ----
    hipMemsetAsync(deg, 0, zero_bytes, stream);
    hist_kernel<<<(NE + 255) / 256, blk, 0, stream>>>(ei, deg);
    bsum_kernel<<<NB, blk, 0, stream>>>(deg, bsum);
    bscan_kernel<<<1, blk, 0, stream>>>(bsum);
    bwrite_kernel<<<NB, blk, 0, stream>>>(deg, bsum, rowptr, cursor);
    scat_idx<<<(NE + 255) / 256, blk, 0, stream>>>(ei, cursor, src_s, perm);
    gather_ea<<<(NE * 4) / 256, blk, 0, stream>>>(ea, perm, ea_s);

    // ---- input projection ----
    inproj_kernel<<<mg1, blk, 0, stream>>>(x, pe, W_in, b_in, hbuf, hb, NN);

    for (int l = 0; l < 4; ++l) {
        float* s1 = stats + (size_t)l * 4096;
        float* s2 = s1 + 2048;

        agg_kernel<<<(NN + 3) / 4, blk, 0, stream>>>(hbuf, hb, rowptr, src_s, ea_s,
                                                     We_edge + (size_t)l * 16 * H,
                                                     be_edge + (size_t)l * H, eps, l, zbuf);

        // GIN pair: t = relu(z@W1g+b1g)@W2g + b2g   (+stats s1)
        gemm_pair<false><<<mg1, blk, 0, stream>>>(
            zbuf, nullptr, wt1g + (size_t)l * 65536, wt2g + (size_t)l * 65536,
            b1g + (size_t)l * H2, b2g + (size_t)l * H,
            nullptr, nullptr, nullptr, s1, tbuf, inv_n, NN);

        // FFN pair: z = relu(bn1(t))+h (staged); u = relu(z@W1f+b1f)@W2f + b2f + z  (+stats s2)
        gemm_pair<true><<<mg1, blk, 0, stream>>>(
            tbuf, hbuf, wt1f + (size_t)l * 65536, wt2f + (size_t)l * 65536,
            b1f + (size_t)l * H2, b2f + (size_t)l * H,
            s1, bn1g + (size_t)l * H, bn1b + (size_t)l * H, s2, tbuf, inv_n, NN);

        // h = bn2(u)
        bn_apply_kernel<<<ew_grid, blk, 0, stream>>>(tbuf, s2, bn2g + (size_t)l * H,
                                                     bn2b + (size_t)l * H, hbuf, hb, inv_n);
    }

    pool_kernel<<<(NN + 255) / 256, blk, 0, stream>>>(hbuf, batch, pool, cnt, NN);
    readout_kernel<<<NG, H, 0, stream>>>(pool, cnt, Wr1, br1, Wr2, br2, out);
}